// Round 1
// baseline (8203.343 us; speedup 1.0000x reference)
//
#include <hip/hip_runtime.h>
#include <math.h>

#define N_NODES 100000
#define D_IN    1000
#define D_OUT   20
#define N_HEAD  8
#define C_ONE   8

static constexpr float kBnEps = 1e-5f;
static constexpr float kSlope = 0.2f;

// ---- ordered-uint encoding of float for atomicMax ----
__device__ __forceinline__ unsigned fenc(float f) {
    unsigned u = __float_as_uint(f);
    return (u & 0x80000000u) ? ~u : (u | 0x80000000u);
}
__device__ __forceinline__ float fdec(unsigned k) {
    return __uint_as_float((k & 0x80000000u) ? (k ^ 0x80000000u) : ~k);
}

// ---- BN column stats: partial sums per row-chunk ----
__global__ void k_bn_partial(const float* __restrict__ x, float* __restrict__ cs,
                             float* __restrict__ cs2, int rows_per_chunk) {
    int col = blockIdx.x * blockDim.x + threadIdx.x;
    if (col >= D_IN) return;
    int r0 = blockIdx.y * rows_per_chunk;
    int r1 = min(r0 + rows_per_chunk, N_NODES);
    float s = 0.f, s2 = 0.f;
    for (int i = r0; i < r1; ++i) {
        float v = x[(size_t)i * D_IN + col];
        s += v; s2 += v * v;
    }
    atomicAdd(&cs[col], s);
    atomicAdd(&cs2[col], s2);
}

__global__ void k_bn_finalize(const float* __restrict__ cs, const float* __restrict__ cs2,
                              const float* __restrict__ gamma, const float* __restrict__ beta,
                              float* __restrict__ scale, float* __restrict__ shift) {
    int k = blockIdx.x * blockDim.x + threadIdx.x;
    if (k >= D_IN) return;
    float mu  = cs[k]  * (1.f / N_NODES);
    float var = cs2[k] * (1.f / N_NODES) - mu * mu;
    float sc  = rsqrtf(var + kBnEps) * gamma[k];
    scale[k] = sc;
    shift[k] = beta[k] - mu * sc;
}

// W1s[k][j] = scale[k] * W1[k][j]
__global__ void k_prep_w1s(const float* __restrict__ W1, const float* __restrict__ scale,
                           float* __restrict__ W1s) {
    int idx = blockIdx.x * blockDim.x + threadIdx.x;
    if (idx >= D_IN * 64) return;
    int k = idx >> 6;
    W1s[idx] = W1[idx] * scale[k];
}

// c1[j] = sum_k shift[k] * W1[k][j]   (BN-shift contribution to h1; GAT bias b1 is added later)
__global__ void k_prep_c1(const float* __restrict__ W1, const float* __restrict__ shift,
                          float* __restrict__ c1) {
    __shared__ float part[4][64];
    int j  = threadIdx.x & 63;
    int kc = threadIdx.x >> 6;
    float acc = 0.f;
    for (int k = kc * 250; k < (kc + 1) * 250; ++k)
        acc += shift[k] * W1[k * 64 + j];
    part[kc][j] = acc;
    __syncthreads();
    if (kc == 0) c1[j] = part[0][j] + part[1][j] + part[2][j] + part[3][j];
}

// h1 = x @ W1s + c1   (64x64 output tile per block, BK=32)
__global__ __launch_bounds__(256) void k_gemm1(const float* __restrict__ x,
                                               const float* __restrict__ W1s,
                                               const float* __restrict__ c1,
                                               float* __restrict__ h1) {
    __shared__ float xs[64][33];
    __shared__ float wsh[32][64];
    int tid = threadIdx.x;
    int row0 = blockIdx.x * 64;
    int ty = tid >> 4, tx = tid & 15;
    float acc[4][4] = {};
    for (int kt = 0; kt < D_IN; kt += 32) {
        #pragma unroll
        for (int t = 0; t < 8; ++t) {
            int e = tid + t * 256;
            int r = e >> 5, kk = e & 31;
            int gr = row0 + r, gk = kt + kk;
            xs[r][kk] = (gr < N_NODES && gk < D_IN) ? x[(size_t)gr * D_IN + gk] : 0.f;
        }
        #pragma unroll
        for (int t = 0; t < 8; ++t) {
            int e = tid + t * 256;
            int kk = e >> 6, c = e & 63;
            int gk = kt + kk;
            wsh[kk][c] = (gk < D_IN) ? W1s[gk * 64 + c] : 0.f;
        }
        __syncthreads();
        #pragma unroll
        for (int kk = 0; kk < 32; ++kk) {
            float a[4], b[4];
            #pragma unroll
            for (int r = 0; r < 4; ++r) a[r] = xs[ty * 4 + r][kk];
            #pragma unroll
            for (int c = 0; c < 4; ++c) b[c] = wsh[kk][tx * 4 + c];
            #pragma unroll
            for (int r = 0; r < 4; ++r)
                #pragma unroll
                for (int c = 0; c < 4; ++c)
                    acc[r][c] += a[r] * b[c];
        }
        __syncthreads();
    }
    #pragma unroll
    for (int r = 0; r < 4; ++r) {
        int gr = row0 + ty * 4 + r;
        if (gr < N_NODES) {
            #pragma unroll
            for (int c = 0; c < 4; ++c)
                h1[(size_t)gr * 64 + tx * 4 + c] = acc[r][c] + c1[tx * 4 + c];
        }
    }
}

// attention logits per node: als[i,h] = sum_c h[i,h,c]*a_src[h,c]; ald likewise
__global__ void k_att_node(const float* __restrict__ h, const float* __restrict__ a_src,
                           const float* __restrict__ a_dst, float* __restrict__ als,
                           float* __restrict__ ald, int C) {
    int idx = blockIdx.x * blockDim.x + threadIdx.x;
    if (idx >= N_NODES * N_HEAD) return;
    int i = idx >> 3, hd = idx & 7;
    const float* hp = h + ((size_t)i * N_HEAD + hd) * C;
    const float* as = a_src + hd * C;
    const float* ad = a_dst + hd * C;
    float s = 0.f, d = 0.f;
    for (int c = 0; c < C; ++c) {
        float v = hp[c];
        s += v * as[c];
        d += v * ad[c];
    }
    als[idx] = s;
    ald[idx] = d;
}

__device__ __forceinline__ void edge_sd(const int* __restrict__ ei, int E, int eid,
                                        int& src, int& dst) {
    if (eid < E) { src = ei[eid]; dst = ei[E + eid]; }
    else { src = eid - E; dst = src; }
}

__global__ void k_edge_max(const int* __restrict__ ei, int E, int TE,
                           const float* __restrict__ als, const float* __restrict__ ald,
                           unsigned* __restrict__ menc) {
    int eid = blockIdx.x * blockDim.x + threadIdx.x;
    if (eid >= TE) return;
    int src, dst; edge_sd(ei, E, eid, src, dst);
    #pragma unroll
    for (int hd = 0; hd < N_HEAD; ++hd) {
        float e = als[src * N_HEAD + hd] + ald[dst * N_HEAD + hd];
        e = e >= 0.f ? e : kSlope * e;
        atomicMax(&menc[dst * N_HEAD + hd], fenc(e));
    }
}

__global__ void k_edge_sum(const int* __restrict__ ei, int E, int TE,
                           const float* __restrict__ als, const float* __restrict__ ald,
                           const unsigned* __restrict__ menc, float* __restrict__ denom) {
    int eid = blockIdx.x * blockDim.x + threadIdx.x;
    if (eid >= TE) return;
    int src, dst; edge_sd(ei, E, eid, src, dst);
    #pragma unroll
    for (int hd = 0; hd < N_HEAD; ++hd) {
        float e = als[src * N_HEAD + hd] + ald[dst * N_HEAD + hd];
        e = e >= 0.f ? e : kSlope * e;
        float ex = expf(e - fdec(menc[dst * N_HEAD + hd]));
        atomicAdd(&denom[dst * N_HEAD + hd], ex);
    }
}

// layer-1 message scatter: thread per (edge, head), 8 atomics each into out1[N,64]
__global__ void k_edge_scatter1(const int* __restrict__ ei, int E, int TE,
                                const float* __restrict__ als, const float* __restrict__ ald,
                                const unsigned* __restrict__ menc, const float* __restrict__ denom,
                                const float* __restrict__ h, float* __restrict__ outacc) {
    int idx = blockIdx.x * blockDim.x + threadIdx.x;
    if (idx >= TE * N_HEAD) return;
    int eid = idx >> 3, hd = idx & 7;
    int src, dst; edge_sd(ei, E, eid, src, dst);
    float e = als[src * N_HEAD + hd] + ald[dst * N_HEAD + hd];
    e = e >= 0.f ? e : kSlope * e;
    float alpha = expf(e - fdec(menc[dst * N_HEAD + hd])) /
                  (denom[dst * N_HEAD + hd] + 1e-16f);
    const float* hp = h + ((size_t)src * N_HEAD + hd) * C_ONE;
    float* op = outacc + ((size_t)dst * N_HEAD + hd) * C_ONE;
    #pragma unroll
    for (int c = 0; c < C_ONE; ++c)
        atomicAdd(&op[c], alpha * hp[c]);
}

// layer-2 message scatter: thread per edge; head-mean folded in; accumulates into d_out[N,20]
__global__ void k_edge_scatter2(const int* __restrict__ ei, int E, int TE,
                                const float* __restrict__ als, const float* __restrict__ ald,
                                const unsigned* __restrict__ menc, const float* __restrict__ denom,
                                const float* __restrict__ h2, float* __restrict__ dout) {
    int eid = blockIdx.x * blockDim.x + threadIdx.x;
    if (eid >= TE) return;
    int src, dst; edge_sd(ei, E, eid, src, dst);
    float alpha[N_HEAD];
    #pragma unroll
    for (int hd = 0; hd < N_HEAD; ++hd) {
        float e = als[src * N_HEAD + hd] + ald[dst * N_HEAD + hd];
        e = e >= 0.f ? e : kSlope * e;
        alpha[hd] = expf(e - fdec(menc[dst * N_HEAD + hd])) /
                    (denom[dst * N_HEAD + hd] + 1e-16f);
    }
    const float* hp = h2 + (size_t)src * (N_HEAD * D_OUT);
    float* op = dout + (size_t)dst * D_OUT;
    #pragma unroll
    for (int c = 0; c < D_OUT; ++c) {
        float v = 0.f;
        #pragma unroll
        for (int hd = 0; hd < N_HEAD; ++hd) v += alpha[hd] * hp[hd * D_OUT + c];
        atomicAdd(&op[c], 0.125f * v);
    }
}

// out1 = elu(out1 + b1), in place
__global__ void k_bias_elu(float* __restrict__ o, const float* __restrict__ b) {
    int idx = blockIdx.x * blockDim.x + threadIdx.x;
    if (idx >= N_NODES * 64) return;
    float v = o[idx] + b[idx & 63];
    o[idx] = v > 0.f ? v : expf(v) - 1.f;
}

// h2 = hin @ W2  (K=64, 160 cols; W2 staged in LDS)
__global__ __launch_bounds__(256) void k_gemm2(const float* __restrict__ hin,
                                               const float* __restrict__ W2,
                                               float* __restrict__ h2) {
    __shared__ float w[64 * 160];
    __shared__ float rows[32][65];
    int tid = threadIdx.x;
    for (int t = tid; t < 64 * 160; t += 256) w[t] = W2[t];
    int r0 = blockIdx.x * 32;
    for (int t = tid; t < 32 * 64; t += 256) {
        int r = t >> 6, c = t & 63;
        rows[r][c] = hin[(size_t)(r0 + r) * 64 + c];
    }
    __syncthreads();
    int r = tid >> 3, g = tid & 7;
    float acc[20] = {};
    for (int k = 0; k < 64; ++k) {
        float a = rows[r][k];
        const float* wp = &w[k * 160 + g * 20];
        #pragma unroll
        for (int c = 0; c < 20; ++c) acc[c] += a * wp[c];
    }
    float* op = &h2[(size_t)(r0 + r) * 160 + g * 20];
    #pragma unroll
    for (int c = 0; c < 20; ++c) op[c] = acc[c];
}

// in-place: out[i,:] = log_softmax(out[i,:] + b2); one wave per node
__global__ void k_final(float* __restrict__ out, const float* __restrict__ b2) {
    int lane = threadIdx.x & 63;
    int node = blockIdx.x * 4 + (threadIdx.x >> 6);
    float v = -INFINITY;
    if (lane < D_OUT) v = out[(size_t)node * D_OUT + lane] + b2[lane];
    float m = v;
    #pragma unroll
    for (int off = 32; off > 0; off >>= 1) m = fmaxf(m, __shfl_xor(m, off));
    float ex = (lane < D_OUT) ? expf(v - m) : 0.f;
    float s = ex;
    #pragma unroll
    for (int off = 32; off > 0; off >>= 1) s += __shfl_xor(s, off);
    if (lane < D_OUT) out[(size_t)node * D_OUT + lane] = v - m - logf(s);
}

extern "C" void kernel_launch(void* const* d_in, const int* in_sizes, int n_in,
                              void* d_out, int out_size, void* d_ws, size_t ws_size,
                              hipStream_t stream) {
    const float* x      = (const float*)d_in[0];
    const int*   ei     = (const int*)d_in[1];
    const float* gamma  = (const float*)d_in[2];
    const float* beta   = (const float*)d_in[3];
    const float* W1     = (const float*)d_in[4];
    const float* a_src1 = (const float*)d_in[5];
    const float* a_dst1 = (const float*)d_in[6];
    const float* b1     = (const float*)d_in[7];
    const float* W2     = (const float*)d_in[8];
    const float* a_src2 = (const float*)d_in[9];
    const float* a_dst2 = (const float*)d_in[10];
    const float* b2     = (const float*)d_in[11];
    float* out = (float*)d_out;
    (void)n_in; (void)out_size; (void)ws_size;

    const int E  = in_sizes[1] / 2;
    const int TE = E + N_NODES;

    char* wsb = (char*)d_ws;
    size_t off = 0;
    auto alloc = [&](size_t bytes) -> void* {
        void* p = wsb + off;
        off += (bytes + 255) & ~(size_t)255;
        return p;
    };
    float*    cs    = (float*)alloc(D_IN * sizeof(float));
    float*    cs2   = (float*)alloc(D_IN * sizeof(float));
    float*    scale = (float*)alloc(D_IN * sizeof(float));
    float*    shift = (float*)alloc(D_IN * sizeof(float));
    float*    W1s   = (float*)alloc((size_t)D_IN * 64 * sizeof(float));
    float*    c1    = (float*)alloc(64 * sizeof(float));
    float*    h1    = (float*)alloc((size_t)N_NODES * 64 * sizeof(float));
    float*    als   = (float*)alloc((size_t)N_NODES * N_HEAD * sizeof(float));
    float*    ald   = (float*)alloc((size_t)N_NODES * N_HEAD * sizeof(float));
    unsigned* menc  = (unsigned*)alloc((size_t)N_NODES * N_HEAD * sizeof(unsigned));
    float*    denom = (float*)alloc((size_t)N_NODES * N_HEAD * sizeof(float));
    float*    out1  = (float*)alloc((size_t)N_NODES * 64 * sizeof(float));
    float*    h2    = (float*)alloc((size_t)N_NODES * 160 * sizeof(float));

    // ---- BN stats + weight folding ----
    hipMemsetAsync(cs, 0, D_IN * sizeof(float), stream);
    hipMemsetAsync(cs2, 0, D_IN * sizeof(float), stream);
    {
        dim3 grid((D_IN + 255) / 256, 256);
        int rpc = (N_NODES + 255) / 256;
        k_bn_partial<<<grid, 256, 0, stream>>>(x, cs, cs2, rpc);
    }
    k_bn_finalize<<<(D_IN + 255) / 256, 256, 0, stream>>>(cs, cs2, gamma, beta, scale, shift);
    k_prep_w1s<<<(D_IN * 64 + 255) / 256, 256, 0, stream>>>(W1, scale, W1s);
    k_prep_c1<<<1, 256, 0, stream>>>(W1, shift, c1);

    // ---- layer 1 ----
    k_gemm1<<<(N_NODES + 63) / 64, 256, 0, stream>>>(x, W1s, c1, h1);
    k_att_node<<<(N_NODES * N_HEAD + 255) / 256, 256, 0, stream>>>(h1, a_src1, a_dst1, als, ald, C_ONE);

    hipMemsetAsync(menc, 0, (size_t)N_NODES * N_HEAD * 4, stream);
    hipMemsetAsync(denom, 0, (size_t)N_NODES * N_HEAD * 4, stream);
    hipMemsetAsync(out1, 0, (size_t)N_NODES * 64 * 4, stream);

    int egrid = (TE + 255) / 256;
    int sgrid = (TE * N_HEAD + 255) / 256;
    k_edge_max<<<egrid, 256, 0, stream>>>(ei, E, TE, als, ald, menc);
    k_edge_sum<<<egrid, 256, 0, stream>>>(ei, E, TE, als, ald, menc, denom);
    k_edge_scatter1<<<sgrid, 256, 0, stream>>>(ei, E, TE, als, ald, menc, denom, h1, out1);
    k_bias_elu<<<(N_NODES * 64 + 255) / 256, 256, 0, stream>>>(out1, b1);

    // ---- layer 2 ----
    k_gemm2<<<N_NODES / 32, 256, 0, stream>>>(out1, W2, h2);
    k_att_node<<<(N_NODES * N_HEAD + 255) / 256, 256, 0, stream>>>(h2, a_src2, a_dst2, als, ald, D_OUT);

    hipMemsetAsync(menc, 0, (size_t)N_NODES * N_HEAD * 4, stream);
    hipMemsetAsync(denom, 0, (size_t)N_NODES * N_HEAD * 4, stream);
    hipMemsetAsync(out, 0, (size_t)N_NODES * D_OUT * 4, stream);

    k_edge_max<<<egrid, 256, 0, stream>>>(ei, E, TE, als, ald, menc);
    k_edge_sum<<<egrid, 256, 0, stream>>>(ei, E, TE, als, ald, menc, denom);
    k_edge_scatter2<<<egrid, 256, 0, stream>>>(ei, E, TE, als, ald, menc, denom, h2, out);

    k_final<<<N_NODES / 4, 256, 0, stream>>>(out, b2);
}

// Round 2
// 1489.480 us; speedup vs baseline: 5.5075x; 5.5075x over previous
//
#include <hip/hip_runtime.h>
#include <math.h>

#define N_NODES 100000
#define D_IN    1000
#define D_OUT   20
#define N_HEAD  8
#define C_ONE   8
#define SCAN_CHUNK 512
#define NCH ((N_NODES + SCAN_CHUNK - 1) / SCAN_CHUNK)

static constexpr float kBnEps = 1e-5f;
static constexpr float kSlope = 0.2f;

// ---- BN column stats: partial sums per row-chunk ----
__global__ void k_bn_partial(const float* __restrict__ x, float* __restrict__ cs,
                             float* __restrict__ cs2, int rows_per_chunk) {
    int col = blockIdx.x * blockDim.x + threadIdx.x;
    if (col >= D_IN) return;
    int r0 = blockIdx.y * rows_per_chunk;
    int r1 = min(r0 + rows_per_chunk, N_NODES);
    float s = 0.f, s2 = 0.f;
    for (int i = r0; i < r1; ++i) {
        float v = x[(size_t)i * D_IN + col];
        s += v; s2 += v * v;
    }
    atomicAdd(&cs[col], s);
    atomicAdd(&cs2[col], s2);
}

__global__ void k_bn_finalize(const float* __restrict__ cs, const float* __restrict__ cs2,
                              const float* __restrict__ gamma, const float* __restrict__ beta,
                              float* __restrict__ scale, float* __restrict__ shift) {
    int k = blockIdx.x * blockDim.x + threadIdx.x;
    if (k >= D_IN) return;
    float mu  = cs[k]  * (1.f / N_NODES);
    float var = cs2[k] * (1.f / N_NODES) - mu * mu;
    float sc  = rsqrtf(var + kBnEps) * gamma[k];
    scale[k] = sc;
    shift[k] = beta[k] - mu * sc;
}

// W1s[k][j] = scale[k] * W1[k][j]
__global__ void k_prep_w1s(const float* __restrict__ W1, const float* __restrict__ scale,
                           float* __restrict__ W1s) {
    int idx = blockIdx.x * blockDim.x + threadIdx.x;
    if (idx >= D_IN * 64) return;
    int k = idx >> 6;
    W1s[idx] = W1[idx] * scale[k];
}

// c1[j] = sum_k shift[k] * W1[k][j]
__global__ void k_prep_c1(const float* __restrict__ W1, const float* __restrict__ shift,
                          float* __restrict__ c1) {
    __shared__ float part[4][64];
    int j  = threadIdx.x & 63;
    int kc = threadIdx.x >> 6;
    float acc = 0.f;
    for (int k = kc * 250; k < (kc + 1) * 250; ++k)
        acc += shift[k] * W1[k * 64 + j];
    part[kc][j] = acc;
    __syncthreads();
    if (kc == 0) c1[j] = part[0][j] + part[1][j] + part[2][j] + part[3][j];
}

// h1 = x @ W1s + c1   (64x64 output tile per block, BK=32)
__global__ __launch_bounds__(256) void k_gemm1(const float* __restrict__ x,
                                               const float* __restrict__ W1s,
                                               const float* __restrict__ c1,
                                               float* __restrict__ h1) {
    __shared__ float xs[64][33];
    __shared__ float wsh[32][64];
    int tid = threadIdx.x;
    int row0 = blockIdx.x * 64;
    int ty = tid >> 4, tx = tid & 15;
    float acc[4][4] = {};
    for (int kt = 0; kt < D_IN; kt += 32) {
        #pragma unroll
        for (int t = 0; t < 8; ++t) {
            int e = tid + t * 256;
            int r = e >> 5, kk = e & 31;
            int gr = row0 + r, gk = kt + kk;
            xs[r][kk] = (gr < N_NODES && gk < D_IN) ? x[(size_t)gr * D_IN + gk] : 0.f;
        }
        #pragma unroll
        for (int t = 0; t < 8; ++t) {
            int e = tid + t * 256;
            int kk = e >> 6, c = e & 63;
            int gk = kt + kk;
            wsh[kk][c] = (gk < D_IN) ? W1s[gk * 64 + c] : 0.f;
        }
        __syncthreads();
        #pragma unroll
        for (int kk = 0; kk < 32; ++kk) {
            float a[4], b[4];
            #pragma unroll
            for (int r = 0; r < 4; ++r) a[r] = xs[ty * 4 + r][kk];
            #pragma unroll
            for (int c = 0; c < 4; ++c) b[c] = wsh[kk][tx * 4 + c];
            #pragma unroll
            for (int r = 0; r < 4; ++r)
                #pragma unroll
                for (int c = 0; c < 4; ++c)
                    acc[r][c] += a[r] * b[c];
        }
        __syncthreads();
    }
    #pragma unroll
    for (int r = 0; r < 4; ++r) {
        int gr = row0 + ty * 4 + r;
        if (gr < N_NODES) {
            #pragma unroll
            for (int c = 0; c < 4; ++c)
                h1[(size_t)gr * 64 + tx * 4 + c] = acc[r][c] + c1[tx * 4 + c];
        }
    }
}

// attention logits per node
__global__ void k_att_node(const float* __restrict__ h, const float* __restrict__ a_src,
                           const float* __restrict__ a_dst, float* __restrict__ als,
                           float* __restrict__ ald, int C) {
    int idx = blockIdx.x * blockDim.x + threadIdx.x;
    if (idx >= N_NODES * N_HEAD) return;
    int i = idx >> 3, hd = idx & 7;
    const float* hp = h + ((size_t)i * N_HEAD + hd) * C;
    const float* as = a_src + hd * C;
    const float* ad = a_dst + hd * C;
    float s = 0.f, d = 0.f;
    for (int c = 0; c < C; ++c) {
        float v = hp[c];
        s += v * as[c];
        d += v * ad[c];
    }
    als[idx] = s;
    ald[idx] = d;
}

// ============ CSR build ============
__global__ void k_deg(const int* __restrict__ ei, int E, int TE, int* __restrict__ deg) {
    int eid = blockIdx.x * blockDim.x + threadIdx.x;
    if (eid >= TE) return;
    int dst = (eid < E) ? ei[E + eid] : (eid - E);
    atomicAdd(&deg[dst], 1);
}

__global__ void k_scan_a(const int* __restrict__ deg, int* __restrict__ csum) {
    __shared__ int red[4];
    int c = blockIdx.x, tid = threadIdx.x;
    int i0 = c * SCAN_CHUNK + tid * 2;
    int a = (i0 < N_NODES) ? deg[i0] : 0;
    int b = (i0 + 1 < N_NODES) ? deg[i0 + 1] : 0;
    int t = a + b;
    #pragma unroll
    for (int d = 1; d < 64; d <<= 1) t += __shfl_xor(t, d);
    if ((tid & 63) == 0) red[tid >> 6] = t;
    __syncthreads();
    if (tid == 0) csum[c] = red[0] + red[1] + red[2] + red[3];
}

__global__ void k_scan_b(int* __restrict__ csum, int total, int* __restrict__ row_start) {
    if (threadIdx.x == 0) {
        int acc = 0;
        for (int i = 0; i < NCH; ++i) { int v = csum[i]; csum[i] = acc; acc += v; }
        row_start[N_NODES] = total;
    }
}

__global__ void k_scan_c(const int* __restrict__ deg, const int* __restrict__ csum,
                         int* __restrict__ row_start, int* __restrict__ cursor) {
    __shared__ int wsum[4];
    int c = blockIdx.x, tid = threadIdx.x;
    int lane = tid & 63, w = tid >> 6;
    int i0 = c * SCAN_CHUNK + tid * 2;
    int a = (i0 < N_NODES) ? deg[i0] : 0;
    int b = (i0 + 1 < N_NODES) ? deg[i0 + 1] : 0;
    int t = a + b;
    int incl = t;
    #pragma unroll
    for (int d = 1; d < 64; d <<= 1) {
        int v = __shfl_up(incl, d);
        if (lane >= d) incl += v;
    }
    if (lane == 63) wsum[w] = incl;
    __syncthreads();
    int wbase = 0;
    for (int k = 0; k < w; ++k) wbase += wsum[k];
    int ex = csum[c] + wbase + incl - t;
    if (i0 < N_NODES)     { row_start[i0] = ex;     cursor[i0] = ex; }
    if (i0 + 1 < N_NODES) { row_start[i0 + 1] = ex + a; cursor[i0 + 1] = ex + a; }
}

__global__ void k_fill(const int* __restrict__ ei, int E, int TE,
                       int* __restrict__ cursor, int* __restrict__ srcs) {
    int eid = blockIdx.x * blockDim.x + threadIdx.x;
    if (eid >= TE) return;
    int src, dst;
    if (eid < E) { src = ei[eid]; dst = ei[E + eid]; }
    else { src = eid - E; dst = src; }
    int pos = atomicAdd(&cursor[dst], 1);
    srcs[pos] = src;
}

// ============ layer-1 gather: max/denom/weighted-gather + bias + ELU ============
__global__ __launch_bounds__(256) void k_gather1(const int* __restrict__ row_start,
                                                 const int* __restrict__ srcs,
                                                 const float* __restrict__ als,
                                                 const float* __restrict__ ald,
                                                 const float* __restrict__ h,
                                                 const float* __restrict__ b1,
                                                 float* __restrict__ out1) {
    int idx = blockIdx.x * blockDim.x + threadIdx.x;
    if (idx >= N_NODES * N_HEAD) return;
    int dst = idx >> 3, hd = idx & 7;
    int beg = row_start[dst], end = row_start[dst + 1];
    float ad = ald[idx];
    float m = -1e30f;
    for (int e = beg; e < end; ++e) {
        int s = srcs[e];
        float v = als[s * N_HEAD + hd] + ad;
        v = v >= 0.f ? v : kSlope * v;
        m = fmaxf(m, v);
    }
    float sum = 0.f;
    for (int e = beg; e < end; ++e) {
        int s = srcs[e];
        float v = als[s * N_HEAD + hd] + ad;
        v = v >= 0.f ? v : kSlope * v;
        sum += expf(v - m);
    }
    float inv = 1.f / (sum + 1e-16f);
    float acc[C_ONE] = {};
    for (int e = beg; e < end; ++e) {
        int s = srcs[e];
        float v = als[s * N_HEAD + hd] + ad;
        v = v >= 0.f ? v : kSlope * v;
        float alpha = expf(v - m) * inv;
        const float* hp = h + ((size_t)s * N_HEAD + hd) * C_ONE;
        #pragma unroll
        for (int c = 0; c < C_ONE; ++c) acc[c] += alpha * hp[c];
    }
    float* op = out1 + (size_t)dst * 64 + hd * C_ONE;
    #pragma unroll
    for (int c = 0; c < C_ONE; ++c) {
        float v = acc[c] + b1[hd * C_ONE + c];
        op[c] = v > 0.f ? v : expf(v) - 1.f;
    }
}

// ============ layer-2 gather + head-mean + bias + log_softmax ============
__global__ __launch_bounds__(256) void k_gather2(const int* __restrict__ row_start,
                                                 const int* __restrict__ srcs,
                                                 const float* __restrict__ als,
                                                 const float* __restrict__ ald,
                                                 const float* __restrict__ h2,
                                                 const float* __restrict__ b2,
                                                 float* __restrict__ out) {
    int idx = blockIdx.x * blockDim.x + threadIdx.x;
    if (idx >= N_NODES * N_HEAD) return;
    int dst = idx >> 3, hd = idx & 7;
    int beg = row_start[dst], end = row_start[dst + 1];
    float ad = ald[idx];
    float m = -1e30f;
    for (int e = beg; e < end; ++e) {
        int s = srcs[e];
        float v = als[s * N_HEAD + hd] + ad;
        v = v >= 0.f ? v : kSlope * v;
        m = fmaxf(m, v);
    }
    float sum = 0.f;
    for (int e = beg; e < end; ++e) {
        int s = srcs[e];
        float v = als[s * N_HEAD + hd] + ad;
        v = v >= 0.f ? v : kSlope * v;
        sum += expf(v - m);
    }
    float inv = 1.f / (sum + 1e-16f);
    float acc[D_OUT] = {};
    for (int e = beg; e < end; ++e) {
        int s = srcs[e];
        float v = als[s * N_HEAD + hd] + ad;
        v = v >= 0.f ? v : kSlope * v;
        float alpha = expf(v - m) * inv;
        const float* hp = h2 + (size_t)s * (N_HEAD * D_OUT) + hd * D_OUT;
        #pragma unroll
        for (int c = 0; c < D_OUT; ++c) acc[c] += alpha * hp[c];
    }
    // head-mean across the 8 consecutive lanes of this dst
    #pragma unroll
    for (int c = 0; c < D_OUT; ++c) {
        float v = acc[c];
        v += __shfl_xor(v, 1);
        v += __shfl_xor(v, 2);
        v += __shfl_xor(v, 4);
        acc[c] = v;
    }
    if (hd == 0) {
        float vals[D_OUT];
        float mx = -1e30f;
        #pragma unroll
        for (int c = 0; c < D_OUT; ++c) {
            vals[c] = 0.125f * acc[c] + b2[c];
            mx = fmaxf(mx, vals[c]);
        }
        float s = 0.f;
        #pragma unroll
        for (int c = 0; c < D_OUT; ++c) s += expf(vals[c] - mx);
        float lse = mx + logf(s);
        float* op = out + (size_t)dst * D_OUT;
        #pragma unroll
        for (int c = 0; c < D_OUT; ++c) op[c] = vals[c] - lse;
    }
}

// h2 = hin @ W2  (K=64, 160 cols; W2 staged in LDS)
__global__ __launch_bounds__(256) void k_gemm2(const float* __restrict__ hin,
                                               const float* __restrict__ W2,
                                               float* __restrict__ h2) {
    __shared__ float w[64 * 160];
    __shared__ float rows[32][65];
    int tid = threadIdx.x;
    for (int t = tid; t < 64 * 160; t += 256) w[t] = W2[t];
    int r0 = blockIdx.x * 32;
    for (int t = tid; t < 32 * 64; t += 256) {
        int r = t >> 6, c = t & 63;
        rows[r][c] = hin[(size_t)(r0 + r) * 64 + c];
    }
    __syncthreads();
    int r = tid >> 3, g = tid & 7;
    float acc[20] = {};
    for (int k = 0; k < 64; ++k) {
        float a = rows[r][k];
        const float* wp = &w[k * 160 + g * 20];
        #pragma unroll
        for (int c = 0; c < 20; ++c) acc[c] += a * wp[c];
    }
    float* op = &h2[(size_t)(r0 + r) * 160 + g * 20];
    #pragma unroll
    for (int c = 0; c < 20; ++c) op[c] = acc[c];
}

extern "C" void kernel_launch(void* const* d_in, const int* in_sizes, int n_in,
                              void* d_out, int out_size, void* d_ws, size_t ws_size,
                              hipStream_t stream) {
    const float* x      = (const float*)d_in[0];
    const int*   ei     = (const int*)d_in[1];
    const float* gamma  = (const float*)d_in[2];
    const float* beta   = (const float*)d_in[3];
    const float* W1     = (const float*)d_in[4];
    const float* a_src1 = (const float*)d_in[5];
    const float* a_dst1 = (const float*)d_in[6];
    const float* b1     = (const float*)d_in[7];
    const float* W2     = (const float*)d_in[8];
    const float* a_src2 = (const float*)d_in[9];
    const float* a_dst2 = (const float*)d_in[10];
    const float* b2     = (const float*)d_in[11];
    float* out = (float*)d_out;
    (void)n_in; (void)out_size; (void)ws_size;

    const int E  = in_sizes[1] / 2;
    const int TE = E + N_NODES;

    char* wsb = (char*)d_ws;
    size_t off = 0;
    auto alloc = [&](size_t bytes) -> void* {
        void* p = wsb + off;
        off += (bytes + 255) & ~(size_t)255;
        return p;
    };
    float* cs    = (float*)alloc(D_IN * sizeof(float));
    float* cs2   = (float*)alloc(D_IN * sizeof(float));
    float* scale = (float*)alloc(D_IN * sizeof(float));
    float* shift = (float*)alloc(D_IN * sizeof(float));
    float* W1s   = (float*)alloc((size_t)D_IN * 64 * sizeof(float));
    float* c1    = (float*)alloc(64 * sizeof(float));
    float* h1    = (float*)alloc((size_t)N_NODES * 64 * sizeof(float));
    float* als   = (float*)alloc((size_t)N_NODES * N_HEAD * sizeof(float));
    float* ald   = (float*)alloc((size_t)N_NODES * N_HEAD * sizeof(float));
    float* out1  = (float*)alloc((size_t)N_NODES * 64 * sizeof(float));
    float* h2    = (float*)alloc((size_t)N_NODES * 160 * sizeof(float));
    int*   deg   = (int*)alloc((size_t)N_NODES * sizeof(int));
    int*   rs    = (int*)alloc((size_t)(N_NODES + 1) * sizeof(int));
    int*   cur   = (int*)alloc((size_t)N_NODES * sizeof(int));
    int*   csum  = (int*)alloc((size_t)NCH * sizeof(int));
    int*   srcs  = (int*)alloc((size_t)TE * sizeof(int));

    int egrid = (TE + 255) / 256;
    int ngrid = (N_NODES * N_HEAD) / 256;  // 800000/256 = 3125 exact

    // ---- CSR build (independent of BN/GEMM work) ----
    hipMemsetAsync(deg, 0, (size_t)N_NODES * sizeof(int), stream);
    k_deg<<<egrid, 256, 0, stream>>>(ei, E, TE, deg);
    k_scan_a<<<NCH, 256, 0, stream>>>(deg, csum);
    k_scan_b<<<1, 64, 0, stream>>>(csum, TE, rs);
    k_scan_c<<<NCH, 256, 0, stream>>>(deg, csum, rs, cur);
    k_fill<<<egrid, 256, 0, stream>>>(ei, E, TE, cur, srcs);

    // ---- BN stats + weight folding ----
    hipMemsetAsync(cs, 0, D_IN * sizeof(float), stream);
    hipMemsetAsync(cs2, 0, D_IN * sizeof(float), stream);
    {
        dim3 grid((D_IN + 255) / 256, 256);
        int rpc = (N_NODES + 255) / 256;
        k_bn_partial<<<grid, 256, 0, stream>>>(x, cs, cs2, rpc);
    }
    k_bn_finalize<<<(D_IN + 255) / 256, 256, 0, stream>>>(cs, cs2, gamma, beta, scale, shift);
    k_prep_w1s<<<(D_IN * 64 + 255) / 256, 256, 0, stream>>>(W1, scale, W1s);
    k_prep_c1<<<1, 256, 0, stream>>>(W1, shift, c1);

    // ---- layer 1 ----
    k_gemm1<<<(N_NODES + 63) / 64, 256, 0, stream>>>(x, W1s, c1, h1);
    k_att_node<<<ngrid, 256, 0, stream>>>(h1, a_src1, a_dst1, als, ald, C_ONE);
    k_gather1<<<ngrid, 256, 0, stream>>>(rs, srcs, als, ald, h1, b1, out1);

    // ---- layer 2 ----
    k_gemm2<<<N_NODES / 32, 256, 0, stream>>>(out1, W2, h2);
    k_att_node<<<ngrid, 256, 0, stream>>>(h2, a_src2, a_dst2, als, ald, D_OUT);
    k_gather2<<<ngrid, 256, 0, stream>>>(rs, srcs, als, ald, h2, b2, out);
}

// Round 3
// 992.188 us; speedup vs baseline: 8.2679x; 1.5012x over previous
//
#include <hip/hip_runtime.h>
#include <math.h>

#define N_NODES 100000
#define D_IN    1000
#define D_OUT   20
#define N_HEAD  8
#define C_ONE   8
#define SCAN_CHUNK 512
#define NCH ((N_NODES + SCAN_CHUNK - 1) / SCAN_CHUNK)

// GEMM1 tiling
#define BM 128
#define BN 64
#define BK 64
#define KPAD 1024
#define KTILES 16

static constexpr float kBnEps = 1e-5f;
static constexpr float kSlope = 0.2f;

typedef __attribute__((ext_vector_type(8))) short short8;
typedef __attribute__((ext_vector_type(4))) float f32x4;

__device__ __forceinline__ unsigned short f2bf(float f) {
    unsigned u = __float_as_uint(f);
    unsigned r = (u + 0x7fffu + ((u >> 16) & 1u)) >> 16;  // RNE
    return (unsigned short)r;
}

// ---- BN column stats: partial sums per row-chunk ----
__global__ void k_bn_partial(const float* __restrict__ x, float* __restrict__ cs,
                             float* __restrict__ cs2, int rows_per_chunk) {
    int col = blockIdx.x * blockDim.x + threadIdx.x;
    if (col >= D_IN) return;
    int r0 = blockIdx.y * rows_per_chunk;
    int r1 = min(r0 + rows_per_chunk, N_NODES);
    float s = 0.f, s2 = 0.f;
    for (int i = r0; i < r1; ++i) {
        float v = x[(size_t)i * D_IN + col];
        s += v; s2 += v * v;
    }
    atomicAdd(&cs[col], s);
    atomicAdd(&cs2[col], s2);
}

__global__ void k_bn_finalize(const float* __restrict__ cs, const float* __restrict__ cs2,
                              const float* __restrict__ gamma, const float* __restrict__ beta,
                              float* __restrict__ scale, float* __restrict__ shift) {
    int k = blockIdx.x * blockDim.x + threadIdx.x;
    if (k >= D_IN) return;
    float mu  = cs[k]  * (1.f / N_NODES);
    float var = cs2[k] * (1.f / N_NODES) - mu * mu;
    float sc  = rsqrtf(var + kBnEps) * gamma[k];
    scale[k] = sc;
    shift[k] = beta[k] - mu * sc;
}

// W1t[n][k] = bf16(scale[k] * W1[k][n]), K zero-padded to 1024
__global__ void k_prep_w1t(const float* __restrict__ W1, const float* __restrict__ scale,
                           short* __restrict__ W1t) {
    int idx = blockIdx.x * blockDim.x + threadIdx.x;
    if (idx >= 64 * KPAD) return;
    int n = idx >> 10, k = idx & (KPAD - 1);
    float v = (k < D_IN) ? W1[k * 64 + n] * scale[k] : 0.f;
    W1t[idx] = (short)f2bf(v);
}

// c1[j] = sum_k shift[k] * W1[k][j]  (f32, exact)
__global__ void k_prep_c1(const float* __restrict__ W1, const float* __restrict__ shift,
                          float* __restrict__ c1) {
    __shared__ float part[4][64];
    int j  = threadIdx.x & 63;
    int kc = threadIdx.x >> 6;
    float acc = 0.f;
    for (int k = kc * 250; k < (kc + 1) * 250; ++k)
        acc += shift[k] * W1[k * 64 + j];
    part[kc][j] = acc;
    __syncthreads();
    if (kc == 0) c1[j] = part[0][j] + part[1][j] + part[2][j] + part[3][j];
}

// ===== h1 = bf16(x) @ W1t + c1 via MFMA; 128x64 tile, BK=64, XOR-swizzled LDS =====
__global__ __launch_bounds__(256) void k_gemm1(const float* __restrict__ x,
                                               const short* __restrict__ W1t,
                                               const float* __restrict__ c1,
                                               float* __restrict__ h1) {
    __shared__ short lA[BM * BK];  // 16 KB, row r at byte r*128, slot swizzle ^(r&7)
    __shared__ short lB[BN * BK];  // 8 KB,  col n at byte n*128, slot swizzle ^(n&7)

    int tid  = threadIdx.x;
    int lane = tid & 63;
    int wave = tid >> 6;
    int l15  = lane & 15, kq = lane >> 4;
    int row0 = blockIdx.x * BM;
    int wm0  = wave * 32;

    f32x4 zero4 = {0.f, 0.f, 0.f, 0.f};
    f32x4 acc[2][4];
    #pragma unroll
    for (int m = 0; m < 2; ++m)
        #pragma unroll
        for (int n = 0; n < 4; ++n) acc[m][n] = zero4;

    int ar = tid >> 4;      // A-stage base row (0..15), +16 per pass
    int akf4 = tid & 15;    // float4 index within row's 64-col K-chunk

    for (int kt = 0; kt < KTILES; ++kt) {
        int k0 = kt * BK;
        // ---- stage A: 128x64 f32 -> bf16, swizzled ----
        bool kok = (k0 + akf4 * 4) < D_IN;
        #pragma unroll
        for (int p = 0; p < 8; ++p) {
            int r = ar + p * 16;
            int gr = row0 + r;
            float4 v = make_float4(0.f, 0.f, 0.f, 0.f);
            if (gr < N_NODES && kok)
                v = *(const float4*)(x + (size_t)gr * D_IN + k0 + akf4 * 4);
            unsigned lo = f2bf(v.x) | ((unsigned)f2bf(v.y) << 16);
            unsigned hi = f2bf(v.z) | ((unsigned)f2bf(v.w) << 16);
            int off = r * 128 + ((((akf4 >> 1) ^ (r & 7)) << 4) | ((akf4 & 1) << 3));
            *(uint2*)((char*)lA + off) = make_uint2(lo, hi);
        }
        // ---- stage B: 64 cols x 64 k bf16, swizzled ----
        #pragma unroll
        for (int c = tid; c < 512; c += 256) {
            int n = c >> 3, s = c & 7;
            short8 v = *(const short8*)((const char*)W1t + n * (KPAD * 2) + k0 * 2 + (s << 4));
            int off = n * 128 + ((s ^ (n & 7)) << 4);
            *(short8*)((char*)lB + off) = v;
        }
        __syncthreads();
        // ---- fragments + MFMA ----
        #pragma unroll
        for (int h = 0; h < 2; ++h) {
            short8 aF[2], bF[4];
            #pragma unroll
            for (int m = 0; m < 2; ++m) {
                int row = wm0 + m * 16 + l15;
                int off = row * 128 + (((((h << 2) + kq)) ^ (row & 7)) << 4);
                aF[m] = *(const short8*)((const char*)lA + off);
            }
            #pragma unroll
            for (int n = 0; n < 4; ++n) {
                int col = n * 16 + l15;
                int off = col * 128 + (((((h << 2) + kq)) ^ (col & 7)) << 4);
                bF[n] = *(const short8*)((const char*)lB + off);
            }
            #pragma unroll
            for (int m = 0; m < 2; ++m)
                #pragma unroll
                for (int n = 0; n < 4; ++n)
                    acc[m][n] = __builtin_amdgcn_mfma_f32_16x16x32_bf16(aF[m], bF[n], acc[m][n], 0, 0, 0);
        }
        __syncthreads();
    }

    // ---- epilogue: +c1, store ----
    float cv[4];
    #pragma unroll
    for (int n = 0; n < 4; ++n) cv[n] = c1[n * 16 + l15];
    #pragma unroll
    for (int m = 0; m < 2; ++m) {
        int rbase = row0 + wm0 + m * 16 + (kq << 2);
        #pragma unroll
        for (int q = 0; q < 4; ++q) {
            int gr = rbase + q;
            if (gr < N_NODES) {
                float* op = h1 + (size_t)gr * 64;
                #pragma unroll
                for (int n = 0; n < 4; ++n)
                    op[n * 16 + l15] = acc[m][n][q] + cv[n];
            }
        }
    }
}

// attention logits per node
__global__ void k_att_node(const float* __restrict__ h, const float* __restrict__ a_src,
                           const float* __restrict__ a_dst, float* __restrict__ als,
                           float* __restrict__ ald, int C) {
    int idx = blockIdx.x * blockDim.x + threadIdx.x;
    if (idx >= N_NODES * N_HEAD) return;
    int i = idx >> 3, hd = idx & 7;
    const float* hp = h + ((size_t)i * N_HEAD + hd) * C;
    const float* as = a_src + hd * C;
    const float* ad = a_dst + hd * C;
    float s = 0.f, d = 0.f;
    for (int c = 0; c < C; ++c) {
        float v = hp[c];
        s += v * as[c];
        d += v * ad[c];
    }
    als[idx] = s;
    ald[idx] = d;
}

// ============ CSR build ============
__global__ void k_deg(const int* __restrict__ ei, int E, int TE, int* __restrict__ deg) {
    int eid = blockIdx.x * blockDim.x + threadIdx.x;
    if (eid >= TE) return;
    int dst = (eid < E) ? ei[E + eid] : (eid - E);
    atomicAdd(&deg[dst], 1);
}

__global__ void k_scan_a(const int* __restrict__ deg, int* __restrict__ csum) {
    __shared__ int red[4];
    int c = blockIdx.x, tid = threadIdx.x;
    int i0 = c * SCAN_CHUNK + tid * 2;
    int a = (i0 < N_NODES) ? deg[i0] : 0;
    int b = (i0 + 1 < N_NODES) ? deg[i0 + 1] : 0;
    int t = a + b;
    #pragma unroll
    for (int d = 1; d < 64; d <<= 1) t += __shfl_xor(t, d);
    if ((tid & 63) == 0) red[tid >> 6] = t;
    __syncthreads();
    if (tid == 0) csum[c] = red[0] + red[1] + red[2] + red[3];
}

__global__ void k_scan_b(int* __restrict__ csum, int total, int* __restrict__ row_start) {
    if (threadIdx.x == 0) {
        int acc = 0;
        for (int i = 0; i < NCH; ++i) { int v = csum[i]; csum[i] = acc; acc += v; }
        row_start[N_NODES] = total;
    }
}

__global__ void k_scan_c(const int* __restrict__ deg, const int* __restrict__ csum,
                         int* __restrict__ row_start, int* __restrict__ cursor) {
    __shared__ int wsum[4];
    int c = blockIdx.x, tid = threadIdx.x;
    int lane = tid & 63, w = tid >> 6;
    int i0 = c * SCAN_CHUNK + tid * 2;
    int a = (i0 < N_NODES) ? deg[i0] : 0;
    int b = (i0 + 1 < N_NODES) ? deg[i0 + 1] : 0;
    int t = a + b;
    int incl = t;
    #pragma unroll
    for (int d = 1; d < 64; d <<= 1) {
        int v = __shfl_up(incl, d);
        if (lane >= d) incl += v;
    }
    if (lane == 63) wsum[w] = incl;
    __syncthreads();
    int wbase = 0;
    for (int k = 0; k < w; ++k) wbase += wsum[k];
    int ex = csum[c] + wbase + incl - t;
    if (i0 < N_NODES)     { row_start[i0] = ex;         cursor[i0] = ex; }
    if (i0 + 1 < N_NODES) { row_start[i0 + 1] = ex + a; cursor[i0 + 1] = ex + a; }
}

__global__ void k_fill(const int* __restrict__ ei, int E, int TE,
                       int* __restrict__ cursor, int* __restrict__ srcs) {
    int eid = blockIdx.x * blockDim.x + threadIdx.x;
    if (eid >= TE) return;
    int src, dst;
    if (eid < E) { src = ei[eid]; dst = ei[E + eid]; }
    else { src = eid - E; dst = src; }
    int pos = atomicAdd(&cursor[dst], 1);
    srcs[pos] = src;
}

// ============ layer-1 gather: max/denom/weighted-gather + bias + ELU ============
__global__ __launch_bounds__(256) void k_gather1(const int* __restrict__ row_start,
                                                 const int* __restrict__ srcs,
                                                 const float* __restrict__ als,
                                                 const float* __restrict__ ald,
                                                 const float* __restrict__ h,
                                                 const float* __restrict__ b1,
                                                 float* __restrict__ out1) {
    int idx = blockIdx.x * blockDim.x + threadIdx.x;
    if (idx >= N_NODES * N_HEAD) return;
    int dst = idx >> 3, hd = idx & 7;
    int beg = row_start[dst], end = row_start[dst + 1];
    float ad = ald[idx];
    float m = -1e30f;
    for (int e = beg; e < end; ++e) {
        int s = srcs[e];
        float v = als[s * N_HEAD + hd] + ad;
        v = v >= 0.f ? v : kSlope * v;
        m = fmaxf(m, v);
    }
    float sum = 0.f;
    for (int e = beg; e < end; ++e) {
        int s = srcs[e];
        float v = als[s * N_HEAD + hd] + ad;
        v = v >= 0.f ? v : kSlope * v;
        sum += expf(v - m);
    }
    float inv = 1.f / (sum + 1e-16f);
    float acc[C_ONE] = {};
    for (int e = beg; e < end; ++e) {
        int s = srcs[e];
        float v = als[s * N_HEAD + hd] + ad;
        v = v >= 0.f ? v : kSlope * v;
        float alpha = expf(v - m) * inv;
        const float* hp = h + ((size_t)s * N_HEAD + hd) * C_ONE;
        #pragma unroll
        for (int c = 0; c < C_ONE; ++c) acc[c] += alpha * hp[c];
    }
    float* op = out1 + (size_t)dst * 64 + hd * C_ONE;
    #pragma unroll
    for (int c = 0; c < C_ONE; ++c) {
        float v = acc[c] + b1[hd * C_ONE + c];
        op[c] = v > 0.f ? v : expf(v) - 1.f;
    }
}

// ============ layer-2 gather + head-mean + bias + log_softmax ============
__global__ __launch_bounds__(256) void k_gather2(const int* __restrict__ row_start,
                                                 const int* __restrict__ srcs,
                                                 const float* __restrict__ als,
                                                 const float* __restrict__ ald,
                                                 const float* __restrict__ h2,
                                                 const float* __restrict__ b2,
                                                 float* __restrict__ out) {
    int idx = blockIdx.x * blockDim.x + threadIdx.x;
    if (idx >= N_NODES * N_HEAD) return;
    int dst = idx >> 3, hd = idx & 7;
    int beg = row_start[dst], end = row_start[dst + 1];
    float ad = ald[idx];
    float m = -1e30f;
    for (int e = beg; e < end; ++e) {
        int s = srcs[e];
        float v = als[s * N_HEAD + hd] + ad;
        v = v >= 0.f ? v : kSlope * v;
        m = fmaxf(m, v);
    }
    float sum = 0.f;
    for (int e = beg; e < end; ++e) {
        int s = srcs[e];
        float v = als[s * N_HEAD + hd] + ad;
        v = v >= 0.f ? v : kSlope * v;
        sum += expf(v - m);
    }
    float inv = 1.f / (sum + 1e-16f);
    float acc[D_OUT] = {};
    for (int e = beg; e < end; ++e) {
        int s = srcs[e];
        float v = als[s * N_HEAD + hd] + ad;
        v = v >= 0.f ? v : kSlope * v;
        float alpha = expf(v - m) * inv;
        const float* hp = h2 + (size_t)s * (N_HEAD * D_OUT) + hd * D_OUT;
        #pragma unroll
        for (int c = 0; c < D_OUT; ++c) acc[c] += alpha * hp[c];
    }
    #pragma unroll
    for (int c = 0; c < D_OUT; ++c) {
        float v = acc[c];
        v += __shfl_xor(v, 1);
        v += __shfl_xor(v, 2);
        v += __shfl_xor(v, 4);
        acc[c] = v;
    }
    if (hd == 0) {
        float vals[D_OUT];
        float mx = -1e30f;
        #pragma unroll
        for (int c = 0; c < D_OUT; ++c) {
            vals[c] = 0.125f * acc[c] + b2[c];
            mx = fmaxf(mx, vals[c]);
        }
        float s = 0.f;
        #pragma unroll
        for (int c = 0; c < D_OUT; ++c) s += expf(vals[c] - mx);
        float lse = mx + logf(s);
        float* op = out + (size_t)dst * D_OUT;
        #pragma unroll
        for (int c = 0; c < D_OUT; ++c) op[c] = vals[c] - lse;
    }
}

// h2 = hin @ W2  (K=64, 160 cols; W2 staged in LDS) — f32, unchanged this round
__global__ __launch_bounds__(256) void k_gemm2(const float* __restrict__ hin,
                                               const float* __restrict__ W2,
                                               float* __restrict__ h2) {
    __shared__ float w[64 * 160];
    __shared__ float rows[32][65];
    int tid = threadIdx.x;
    for (int t = tid; t < 64 * 160; t += 256) w[t] = W2[t];
    int r0 = blockIdx.x * 32;
    for (int t = tid; t < 32 * 64; t += 256) {
        int r = t >> 6, c = t & 63;
        rows[r][c] = hin[(size_t)(r0 + r) * 64 + c];
    }
    __syncthreads();
    int r = tid >> 3, g = tid & 7;
    float acc[20] = {};
    for (int k = 0; k < 64; ++k) {
        float a = rows[r][k];
        const float* wp = &w[k * 160 + g * 20];
        #pragma unroll
        for (int c = 0; c < 20; ++c) acc[c] += a * wp[c];
    }
    float* op = &h2[(size_t)(r0 + r) * 160 + g * 20];
    #pragma unroll
    for (int c = 0; c < 20; ++c) op[c] = acc[c];
}

extern "C" void kernel_launch(void* const* d_in, const int* in_sizes, int n_in,
                              void* d_out, int out_size, void* d_ws, size_t ws_size,
                              hipStream_t stream) {
    const float* x      = (const float*)d_in[0];
    const int*   ei     = (const int*)d_in[1];
    const float* gamma  = (const float*)d_in[2];
    const float* beta   = (const float*)d_in[3];
    const float* W1     = (const float*)d_in[4];
    const float* a_src1 = (const float*)d_in[5];
    const float* a_dst1 = (const float*)d_in[6];
    const float* b1     = (const float*)d_in[7];
    const float* W2     = (const float*)d_in[8];
    const float* a_src2 = (const float*)d_in[9];
    const float* a_dst2 = (const float*)d_in[10];
    const float* b2     = (const float*)d_in[11];
    float* out = (float*)d_out;
    (void)n_in; (void)out_size; (void)ws_size;

    const int E  = in_sizes[1] / 2;
    const int TE = E + N_NODES;

    char* wsb = (char*)d_ws;
    size_t off = 0;
    auto alloc = [&](size_t bytes) -> void* {
        void* p = wsb + off;
        off += (bytes + 255) & ~(size_t)255;
        return p;
    };
    float* cs    = (float*)alloc(D_IN * sizeof(float));
    float* cs2   = (float*)alloc(D_IN * sizeof(float));
    float* scale = (float*)alloc(D_IN * sizeof(float));
    float* shift = (float*)alloc(D_IN * sizeof(float));
    short* W1t   = (short*)alloc((size_t)64 * KPAD * sizeof(short));
    float* c1    = (float*)alloc(64 * sizeof(float));
    float* h1    = (float*)alloc((size_t)N_NODES * 64 * sizeof(float));
    float* als   = (float*)alloc((size_t)N_NODES * N_HEAD * sizeof(float));
    float* ald   = (float*)alloc((size_t)N_NODES * N_HEAD * sizeof(float));
    float* out1  = (float*)alloc((size_t)N_NODES * 64 * sizeof(float));
    float* h2    = (float*)alloc((size_t)N_NODES * 160 * sizeof(float));
    int*   deg   = (int*)alloc((size_t)N_NODES * sizeof(int));
    int*   rs    = (int*)alloc((size_t)(N_NODES + 1) * sizeof(int));
    int*   cur   = (int*)alloc((size_t)N_NODES * sizeof(int));
    int*   csum  = (int*)alloc((size_t)NCH * sizeof(int));
    int*   srcs  = (int*)alloc((size_t)TE * sizeof(int));

    int egrid = (TE + 255) / 256;
    int ngrid = (N_NODES * N_HEAD) / 256;

    // ---- CSR build ----
    hipMemsetAsync(deg, 0, (size_t)N_NODES * sizeof(int), stream);
    k_deg<<<egrid, 256, 0, stream>>>(ei, E, TE, deg);
    k_scan_a<<<NCH, 256, 0, stream>>>(deg, csum);
    k_scan_b<<<1, 64, 0, stream>>>(csum, TE, rs);
    k_scan_c<<<NCH, 256, 0, stream>>>(deg, csum, rs, cur);
    k_fill<<<egrid, 256, 0, stream>>>(ei, E, TE, cur, srcs);

    // ---- BN stats + weight folding ----
    hipMemsetAsync(cs, 0, D_IN * sizeof(float), stream);
    hipMemsetAsync(cs2, 0, D_IN * sizeof(float), stream);
    {
        dim3 grid((D_IN + 255) / 256, 256);
        int rpc = (N_NODES + 255) / 256;
        k_bn_partial<<<grid, 256, 0, stream>>>(x, cs, cs2, rpc);
    }
    k_bn_finalize<<<(D_IN + 255) / 256, 256, 0, stream>>>(cs, cs2, gamma, beta, scale, shift);
    k_prep_w1t<<<(64 * KPAD) / 256, 256, 0, stream>>>(W1, scale, W1t);
    k_prep_c1<<<1, 256, 0, stream>>>(W1, shift, c1);

    // ---- layer 1 ----
    k_gemm1<<<(N_NODES + BM - 1) / BM, 256, 0, stream>>>(x, W1t, c1, h1);
    k_att_node<<<ngrid, 256, 0, stream>>>(h1, a_src1, a_dst1, als, ald, C_ONE);
    k_gather1<<<ngrid, 256, 0, stream>>>(rs, srcs, als, ald, h1, b1, out1);

    // ---- layer 2 ----
    k_gemm2<<<N_NODES / 32, 256, 0, stream>>>(out1, W2, h2);
    k_att_node<<<ngrid, 256, 0, stream>>>(h2, a_src2, a_dst2, als, ald, D_OUT);
    k_gather2<<<ngrid, 256, 0, stream>>>(rs, srcs, als, ald, h2, b2, out);
}

// Round 4
// 920.082 us; speedup vs baseline: 8.9159x; 1.0784x over previous
//
#include <hip/hip_runtime.h>
#include <math.h>

#define N_NODES 100000
#define D_IN    1000
#define D_OUT   20
#define N_HEAD  8
#define C_ONE   8
#define SCAN_CHUNK 512
#define NCH ((N_NODES + SCAN_CHUNK - 1) / SCAN_CHUNK)

// GEMM1 tiling
#define BM 128
#define BN 64
#define BK 64
#define KPAD 1024
#define KTILES 16

static constexpr float kBnEps = 1e-5f;
static constexpr float kSlope = 0.2f;

typedef __attribute__((ext_vector_type(8))) short short8;
typedef __attribute__((ext_vector_type(4))) float f32x4;

__device__ __forceinline__ unsigned short f2bf(float f) {
    unsigned u = __float_as_uint(f);
    unsigned r = (u + 0x7fffu + ((u >> 16) & 1u)) >> 16;  // RNE
    return (unsigned short)r;
}
__device__ __forceinline__ float bf2f(unsigned short s) {
    unsigned u = ((unsigned)s) << 16;
    return __uint_as_float(u);
}

// ---- BN column stats: float4 columns per thread, 100-row chunks ----
__global__ __launch_bounds__(256) void k_bn_partial(const float* __restrict__ x,
                                                    float* __restrict__ cs,
                                                    float* __restrict__ cs2,
                                                    int rows_per_chunk) {
    int c4 = threadIdx.x;
    if (c4 >= 250) return;
    int r0 = blockIdx.x * rows_per_chunk;
    int r1 = min(r0 + rows_per_chunk, N_NODES);
    float sx = 0.f, sy = 0.f, sz = 0.f, sw = 0.f;
    float qx = 0.f, qy = 0.f, qz = 0.f, qw = 0.f;
    const char* base = (const char*)(x + (size_t)c4 * 4);
    #pragma unroll 4
    for (int i = r0; i < r1; ++i) {
        float4 v = *(const float4*)(base + (size_t)i * (D_IN * 4));
        sx += v.x; sy += v.y; sz += v.z; sw += v.w;
        qx += v.x * v.x; qy += v.y * v.y; qz += v.z * v.z; qw += v.w * v.w;
    }
    atomicAdd(&cs[c4 * 4 + 0], sx);
    atomicAdd(&cs[c4 * 4 + 1], sy);
    atomicAdd(&cs[c4 * 4 + 2], sz);
    atomicAdd(&cs[c4 * 4 + 3], sw);
    atomicAdd(&cs2[c4 * 4 + 0], qx);
    atomicAdd(&cs2[c4 * 4 + 1], qy);
    atomicAdd(&cs2[c4 * 4 + 2], qz);
    atomicAdd(&cs2[c4 * 4 + 3], qw);
}

__global__ void k_bn_finalize(const float* __restrict__ cs, const float* __restrict__ cs2,
                              const float* __restrict__ gamma, const float* __restrict__ beta,
                              float* __restrict__ scale, float* __restrict__ shift) {
    int k = blockIdx.x * blockDim.x + threadIdx.x;
    if (k >= D_IN) return;
    float mu  = cs[k]  * (1.f / N_NODES);
    float var = cs2[k] * (1.f / N_NODES) - mu * mu;
    float sc  = rsqrtf(var + kBnEps) * gamma[k];
    scale[k] = sc;
    shift[k] = beta[k] - mu * sc;
}

// W1t[n][k] = bf16(scale[k] * W1[k][n]), K zero-padded to 1024
__global__ void k_prep_w1t(const float* __restrict__ W1, const float* __restrict__ scale,
                           short* __restrict__ W1t) {
    int idx = blockIdx.x * blockDim.x + threadIdx.x;
    if (idx >= 64 * KPAD) return;
    int n = idx >> 10, k = idx & (KPAD - 1);
    float v = (k < D_IN) ? W1[k * 64 + n] * scale[k] : 0.f;
    W1t[idx] = (short)f2bf(v);
}

// W2t[n][k] = bf16(W2[k][n]);  W2 is [64][160]
__global__ void k_prep_w2t(const float* __restrict__ W2, short* __restrict__ W2t) {
    int idx = blockIdx.x * blockDim.x + threadIdx.x;
    if (idx >= 160 * 64) return;
    int n = idx >> 6, k = idx & 63;
    W2t[idx] = (short)f2bf(W2[k * 160 + n]);
}

// c1[j] = sum_k shift[k] * W1[k][j]  (f32, exact)
__global__ void k_prep_c1(const float* __restrict__ W1, const float* __restrict__ shift,
                          float* __restrict__ c1) {
    __shared__ float part[4][64];
    int j  = threadIdx.x & 63;
    int kc = threadIdx.x >> 6;
    float acc = 0.f;
    for (int k = kc * 250; k < (kc + 1) * 250; ++k)
        acc += shift[k] * W1[k * 64 + j];
    part[kc][j] = acc;
    __syncthreads();
    if (kc == 0) c1[j] = part[0][j] + part[1][j] + part[2][j] + part[3][j];
}

// ===== h1 = bf16(x) @ W1t + c1 via MFMA; 128x64 tile, BK=64, XOR-swizzled LDS =====
__global__ __launch_bounds__(256) void k_gemm1(const float* __restrict__ x,
                                               const short* __restrict__ W1t,
                                               const float* __restrict__ c1,
                                               float* __restrict__ h1) {
    __shared__ short lA[BM * BK];
    __shared__ short lB[BN * BK];

    int tid  = threadIdx.x;
    int lane = tid & 63;
    int wave = tid >> 6;
    int l15  = lane & 15, kq = lane >> 4;
    int row0 = blockIdx.x * BM;
    int wm0  = wave * 32;

    f32x4 zero4 = {0.f, 0.f, 0.f, 0.f};
    f32x4 acc[2][4];
    #pragma unroll
    for (int m = 0; m < 2; ++m)
        #pragma unroll
        for (int n = 0; n < 4; ++n) acc[m][n] = zero4;

    int ar = tid >> 4;
    int akf4 = tid & 15;

    for (int kt = 0; kt < KTILES; ++kt) {
        int k0 = kt * BK;
        bool kok = (k0 + akf4 * 4) < D_IN;
        #pragma unroll
        for (int p = 0; p < 8; ++p) {
            int r = ar + p * 16;
            int gr = row0 + r;
            float4 v = make_float4(0.f, 0.f, 0.f, 0.f);
            if (gr < N_NODES && kok)
                v = *(const float4*)(x + (size_t)gr * D_IN + k0 + akf4 * 4);
            unsigned lo = f2bf(v.x) | ((unsigned)f2bf(v.y) << 16);
            unsigned hi = f2bf(v.z) | ((unsigned)f2bf(v.w) << 16);
            int off = r * 128 + ((((akf4 >> 1) ^ (r & 7)) << 4) | ((akf4 & 1) << 3));
            *(uint2*)((char*)lA + off) = make_uint2(lo, hi);
        }
        #pragma unroll
        for (int c = tid; c < 512; c += 256) {
            int n = c >> 3, s = c & 7;
            short8 v = *(const short8*)((const char*)W1t + n * (KPAD * 2) + k0 * 2 + (s << 4));
            int off = n * 128 + ((s ^ (n & 7)) << 4);
            *(short8*)((char*)lB + off) = v;
        }
        __syncthreads();
        #pragma unroll
        for (int h = 0; h < 2; ++h) {
            short8 aF[2], bF[4];
            #pragma unroll
            for (int m = 0; m < 2; ++m) {
                int row = wm0 + m * 16 + l15;
                int off = row * 128 + (((((h << 2) + kq)) ^ (row & 7)) << 4);
                aF[m] = *(const short8*)((const char*)lA + off);
            }
            #pragma unroll
            for (int n = 0; n < 4; ++n) {
                int col = n * 16 + l15;
                int off = col * 128 + (((((h << 2) + kq)) ^ (col & 7)) << 4);
                bF[n] = *(const short8*)((const char*)lB + off);
            }
            #pragma unroll
            for (int m = 0; m < 2; ++m)
                #pragma unroll
                for (int n = 0; n < 4; ++n)
                    acc[m][n] = __builtin_amdgcn_mfma_f32_16x16x32_bf16(aF[m], bF[n], acc[m][n], 0, 0, 0);
        }
        __syncthreads();
    }

    float cv[4];
    #pragma unroll
    for (int n = 0; n < 4; ++n) cv[n] = c1[n * 16 + l15];
    #pragma unroll
    for (int m = 0; m < 2; ++m) {
        int rbase = row0 + wm0 + m * 16 + (kq << 2);
        #pragma unroll
        for (int q = 0; q < 4; ++q) {
            int gr = rbase + q;
            if (gr < N_NODES) {
                float* op = h1 + (size_t)gr * 64;
                #pragma unroll
                for (int n = 0; n < 4; ++n)
                    op[n * 16 + l15] = acc[m][n][q] + cv[n];
            }
        }
    }
}

// ===== h2 = out1b(bf16) @ W2t + 0; 128x160 tile, K=64, XOR-swizzled LDS =====
__global__ __launch_bounds__(256) void k_gemm2(const short* __restrict__ out1b,
                                               const short* __restrict__ W2t,
                                               float* __restrict__ h2) {
    __shared__ short lA[128 * 64];   // 16 KB
    __shared__ short lB[160 * 64];   // 20 KB

    int tid  = threadIdx.x;
    int lane = tid & 63;
    int wave = tid >> 6;
    int l15  = lane & 15, kq = lane >> 4;
    int row0 = blockIdx.x * 128;
    int wm0  = wave * 32;

    // stage A: 128 rows x 64 k bf16 = 1024 16B-chunks
    #pragma unroll
    for (int p = 0; p < 4; ++p) {
        int idx = tid + p * 256;
        int r = idx >> 3, s = idx & 7;
        int gr = row0 + r;
        short8 v = {};
        if (gr < N_NODES)
            v = *(const short8*)((const char*)out1b + (size_t)gr * 128 + (s << 4));
        int off = r * 128 + ((s ^ (r & 7)) << 4);
        *(short8*)((char*)lA + off) = v;
    }
    // stage B: 160 cols x 64 k = 1280 chunks
    #pragma unroll
    for (int p = 0; p < 5; ++p) {
        int idx = tid + p * 256;
        int n = idx >> 3, s = idx & 7;
        short8 v = *(const short8*)((const char*)W2t + n * 128 + (s << 4));
        int off = n * 128 + ((s ^ (n & 7)) << 4);
        *(short8*)((char*)lB + off) = v;
    }
    __syncthreads();

    f32x4 zero4 = {0.f, 0.f, 0.f, 0.f};
    f32x4 acc[2][10];
    #pragma unroll
    for (int m = 0; m < 2; ++m)
        #pragma unroll
        for (int n = 0; n < 10; ++n) acc[m][n] = zero4;

    #pragma unroll
    for (int h = 0; h < 2; ++h) {
        short8 aF[2], bF[10];
        #pragma unroll
        for (int m = 0; m < 2; ++m) {
            int row = wm0 + m * 16 + l15;
            int off = row * 128 + ((((h << 2) + kq) ^ (row & 7)) << 4);
            aF[m] = *(const short8*)((const char*)lA + off);
        }
        #pragma unroll
        for (int n = 0; n < 10; ++n) {
            int col = n * 16 + l15;
            int off = col * 128 + ((((h << 2) + kq) ^ (col & 7)) << 4);
            bF[n] = *(const short8*)((const char*)lB + off);
        }
        #pragma unroll
        for (int m = 0; m < 2; ++m)
            #pragma unroll
            for (int n = 0; n < 10; ++n)
                acc[m][n] = __builtin_amdgcn_mfma_f32_16x16x32_bf16(aF[m], bF[n], acc[m][n], 0, 0, 0);
    }

    #pragma unroll
    for (int m = 0; m < 2; ++m) {
        int rbase = row0 + wm0 + m * 16 + (kq << 2);
        #pragma unroll
        for (int q = 0; q < 4; ++q) {
            int gr = rbase + q;
            if (gr < N_NODES) {
                float* op = h2 + (size_t)gr * 160;
                #pragma unroll
                for (int n = 0; n < 10; ++n)
                    op[n * 16 + l15] = acc[m][n][q];
            }
        }
    }
}

// attention logits per node
__global__ void k_att_node(const float* __restrict__ h, const float* __restrict__ a_src,
                           const float* __restrict__ a_dst, float* __restrict__ als,
                           float* __restrict__ ald, int C) {
    int idx = blockIdx.x * blockDim.x + threadIdx.x;
    if (idx >= N_NODES * N_HEAD) return;
    int i = idx >> 3, hd = idx & 7;
    const float* hp = h + ((size_t)i * N_HEAD + hd) * C;
    const float* as = a_src + hd * C;
    const float* ad = a_dst + hd * C;
    float s = 0.f, d = 0.f;
    for (int c = 0; c < C; ++c) {
        float v = hp[c];
        s += v * as[c];
        d += v * ad[c];
    }
    als[idx] = s;
    ald[idx] = d;
}

// ============ CSR build ============
__global__ void k_deg(const int* __restrict__ ei, int E, int TE, int* __restrict__ deg) {
    int eid = blockIdx.x * blockDim.x + threadIdx.x;
    if (eid >= TE) return;
    int dst = (eid < E) ? ei[E + eid] : (eid - E);
    atomicAdd(&deg[dst], 1);
}

__global__ void k_scan_a(const int* __restrict__ deg, int* __restrict__ csum) {
    __shared__ int red[4];
    int c = blockIdx.x, tid = threadIdx.x;
    int i0 = c * SCAN_CHUNK + tid * 2;
    int a = (i0 < N_NODES) ? deg[i0] : 0;
    int b = (i0 + 1 < N_NODES) ? deg[i0 + 1] : 0;
    int t = a + b;
    #pragma unroll
    for (int d = 1; d < 64; d <<= 1) t += __shfl_xor(t, d);
    if ((tid & 63) == 0) red[tid >> 6] = t;
    __syncthreads();
    if (tid == 0) csum[c] = red[0] + red[1] + red[2] + red[3];
}

__global__ void k_scan_b(int* __restrict__ csum, int total, int* __restrict__ row_start) {
    if (threadIdx.x == 0) {
        int acc = 0;
        for (int i = 0; i < NCH; ++i) { int v = csum[i]; csum[i] = acc; acc += v; }
        row_start[N_NODES] = total;
    }
}

__global__ void k_scan_c(const int* __restrict__ deg, const int* __restrict__ csum,
                         int* __restrict__ row_start, int* __restrict__ cursor) {
    __shared__ int wsum[4];
    int c = blockIdx.x, tid = threadIdx.x;
    int lane = tid & 63, w = tid >> 6;
    int i0 = c * SCAN_CHUNK + tid * 2;
    int a = (i0 < N_NODES) ? deg[i0] : 0;
    int b = (i0 + 1 < N_NODES) ? deg[i0 + 1] : 0;
    int t = a + b;
    int incl = t;
    #pragma unroll
    for (int d = 1; d < 64; d <<= 1) {
        int v = __shfl_up(incl, d);
        if (lane >= d) incl += v;
    }
    if (lane == 63) wsum[w] = incl;
    __syncthreads();
    int wbase = 0;
    for (int k = 0; k < w; ++k) wbase += wsum[k];
    int ex = csum[c] + wbase + incl - t;
    if (i0 < N_NODES)     { row_start[i0] = ex;         cursor[i0] = ex; }
    if (i0 + 1 < N_NODES) { row_start[i0 + 1] = ex + a; cursor[i0 + 1] = ex + a; }
}

__global__ void k_fill(const int* __restrict__ ei, int E, int TE,
                       int* __restrict__ cursor, int* __restrict__ srcs) {
    int eid = blockIdx.x * blockDim.x + threadIdx.x;
    if (eid >= TE) return;
    int src, dst;
    if (eid < E) { src = ei[eid]; dst = ei[E + eid]; }
    else { src = eid - E; dst = src; }
    int pos = atomicAdd(&cursor[dst], 1);
    srcs[pos] = src;
}

// ============ layer-1 gather: max/denom/weighted-gather + bias + ELU -> bf16 out1 ============
__global__ __launch_bounds__(256) void k_gather1(const int* __restrict__ row_start,
                                                 const int* __restrict__ srcs,
                                                 const float* __restrict__ als,
                                                 const float* __restrict__ ald,
                                                 const float* __restrict__ h,
                                                 const float* __restrict__ b1,
                                                 short* __restrict__ out1b) {
    int idx = blockIdx.x * blockDim.x + threadIdx.x;
    if (idx >= N_NODES * N_HEAD) return;
    int dst = idx >> 3, hd = idx & 7;
    int beg = row_start[dst], end = row_start[dst + 1];
    float ad = ald[idx];
    float m = -1e30f;
    for (int e = beg; e < end; ++e) {
        int s = srcs[e];
        float v = als[s * N_HEAD + hd] + ad;
        v = v >= 0.f ? v : kSlope * v;
        m = fmaxf(m, v);
    }
    float sum = 0.f;
    for (int e = beg; e < end; ++e) {
        int s = srcs[e];
        float v = als[s * N_HEAD + hd] + ad;
        v = v >= 0.f ? v : kSlope * v;
        sum += expf(v - m);
    }
    float inv = 1.f / (sum + 1e-16f);
    float acc[C_ONE] = {};
    for (int e = beg; e < end; ++e) {
        int s = srcs[e];
        float v = als[s * N_HEAD + hd] + ad;
        v = v >= 0.f ? v : kSlope * v;
        float alpha = expf(v - m) * inv;
        const float* hp = h + ((size_t)s * N_HEAD + hd) * C_ONE;
        #pragma unroll
        for (int c = 0; c < C_ONE; ++c) acc[c] += alpha * hp[c];
    }
    short8 o;
    #pragma unroll
    for (int c = 0; c < C_ONE; ++c) {
        float v = acc[c] + b1[hd * C_ONE + c];
        v = v > 0.f ? v : expf(v) - 1.f;
        o[c] = (short)f2bf(v);
    }
    *(short8*)((char*)out1b + (size_t)dst * 128 + hd * 16) = o;
}

// ============ layer-2 gather + head-mean + bias + log_softmax ============
__global__ __launch_bounds__(256) void k_gather2(const int* __restrict__ row_start,
                                                 const int* __restrict__ srcs,
                                                 const float* __restrict__ als,
                                                 const float* __restrict__ ald,
                                                 const float* __restrict__ h2,
                                                 const float* __restrict__ b2,
                                                 float* __restrict__ out) {
    int idx = blockIdx.x * blockDim.x + threadIdx.x;
    if (idx >= N_NODES * N_HEAD) return;
    int dst = idx >> 3, hd = idx & 7;
    int beg = row_start[dst], end = row_start[dst + 1];
    float ad = ald[idx];
    float m = -1e30f;
    for (int e = beg; e < end; ++e) {
        int s = srcs[e];
        float v = als[s * N_HEAD + hd] + ad;
        v = v >= 0.f ? v : kSlope * v;
        m = fmaxf(m, v);
    }
    float sum = 0.f;
    for (int e = beg; e < end; ++e) {
        int s = srcs[e];
        float v = als[s * N_HEAD + hd] + ad;
        v = v >= 0.f ? v : kSlope * v;
        sum += expf(v - m);
    }
    float inv = 1.f / (sum + 1e-16f);
    float acc[D_OUT] = {};
    for (int e = beg; e < end; ++e) {
        int s = srcs[e];
        float v = als[s * N_HEAD + hd] + ad;
        v = v >= 0.f ? v : kSlope * v;
        float alpha = expf(v - m) * inv;
        const float* hp = h2 + (size_t)s * 160 + hd * D_OUT;
        #pragma unroll
        for (int c = 0; c < D_OUT; ++c) acc[c] += alpha * hp[c];
    }
    #pragma unroll
    for (int c = 0; c < D_OUT; ++c) {
        float v = acc[c];
        v += __shfl_xor(v, 1);
        v += __shfl_xor(v, 2);
        v += __shfl_xor(v, 4);
        acc[c] = v;
    }
    if (hd == 0) {
        float vals[D_OUT];
        float mx = -1e30f;
        #pragma unroll
        for (int c = 0; c < D_OUT; ++c) {
            vals[c] = 0.125f * acc[c] + b2[c];
            mx = fmaxf(mx, vals[c]);
        }
        float s = 0.f;
        #pragma unroll
        for (int c = 0; c < D_OUT; ++c) s += expf(vals[c] - mx);
        float lse = mx + logf(s);
        float* op = out + (size_t)dst * D_OUT;
        #pragma unroll
        for (int c = 0; c < D_OUT; ++c) op[c] = vals[c] - lse;
    }
}

extern "C" void kernel_launch(void* const* d_in, const int* in_sizes, int n_in,
                              void* d_out, int out_size, void* d_ws, size_t ws_size,
                              hipStream_t stream) {
    const float* x      = (const float*)d_in[0];
    const int*   ei     = (const int*)d_in[1];
    const float* gamma  = (const float*)d_in[2];
    const float* beta   = (const float*)d_in[3];
    const float* W1     = (const float*)d_in[4];
    const float* a_src1 = (const float*)d_in[5];
    const float* a_dst1 = (const float*)d_in[6];
    const float* b1     = (const float*)d_in[7];
    const float* W2     = (const float*)d_in[8];
    const float* a_src2 = (const float*)d_in[9];
    const float* a_dst2 = (const float*)d_in[10];
    const float* b2     = (const float*)d_in[11];
    float* out = (float*)d_out;
    (void)n_in; (void)out_size; (void)ws_size;

    const int E  = in_sizes[1] / 2;
    const int TE = E + N_NODES;

    char* wsb = (char*)d_ws;
    size_t off = 0;
    auto alloc = [&](size_t bytes) -> void* {
        void* p = wsb + off;
        off += (bytes + 255) & ~(size_t)255;
        return p;
    };
    float* cs    = (float*)alloc(D_IN * sizeof(float));
    float* cs2   = (float*)alloc(D_IN * sizeof(float));
    float* scale = (float*)alloc(D_IN * sizeof(float));
    float* shift = (float*)alloc(D_IN * sizeof(float));
    short* W1t   = (short*)alloc((size_t)64 * KPAD * sizeof(short));
    short* W2t   = (short*)alloc((size_t)160 * 64 * sizeof(short));
    float* c1    = (float*)alloc(64 * sizeof(float));
    float* h1    = (float*)alloc((size_t)N_NODES * 64 * sizeof(float));
    float* als   = (float*)alloc((size_t)N_NODES * N_HEAD * sizeof(float));
    float* ald   = (float*)alloc((size_t)N_NODES * N_HEAD * sizeof(float));
    short* out1b = (short*)alloc((size_t)N_NODES * 64 * sizeof(short));
    float* h2    = (float*)alloc((size_t)N_NODES * 160 * sizeof(float));
    int*   deg   = (int*)alloc((size_t)N_NODES * sizeof(int));
    int*   rs    = (int*)alloc((size_t)(N_NODES + 1) * sizeof(int));
    int*   cur   = (int*)alloc((size_t)N_NODES * sizeof(int));
    int*   csum  = (int*)alloc((size_t)NCH * sizeof(int));
    int*   srcs  = (int*)alloc((size_t)TE * sizeof(int));

    int egrid = (TE + 255) / 256;
    int ngrid = (N_NODES * N_HEAD) / 256;

    // ---- CSR build ----
    hipMemsetAsync(deg, 0, (size_t)N_NODES * sizeof(int), stream);
    k_deg<<<egrid, 256, 0, stream>>>(ei, E, TE, deg);
    k_scan_a<<<NCH, 256, 0, stream>>>(deg, csum);
    k_scan_b<<<1, 64, 0, stream>>>(csum, TE, rs);
    k_scan_c<<<NCH, 256, 0, stream>>>(deg, csum, rs, cur);
    k_fill<<<egrid, 256, 0, stream>>>(ei, E, TE, cur, srcs);

    // ---- BN stats + weight folding ----
    hipMemsetAsync(cs, 0, D_IN * sizeof(float), stream);
    hipMemsetAsync(cs2, 0, D_IN * sizeof(float), stream);
    k_bn_partial<<<1000, 256, 0, stream>>>(x, cs, cs2, 100);
    k_bn_finalize<<<(D_IN + 255) / 256, 256, 0, stream>>>(cs, cs2, gamma, beta, scale, shift);
    k_prep_w1t<<<(64 * KPAD) / 256, 256, 0, stream>>>(W1, scale, W1t);
    k_prep_w2t<<<(160 * 64) / 256, 256, 0, stream>>>(W2, W2t);
    k_prep_c1<<<1, 256, 0, stream>>>(W1, shift, c1);

    // ---- layer 1 ----
    k_gemm1<<<(N_NODES + BM - 1) / BM, 256, 0, stream>>>(x, W1t, c1, h1);
    k_att_node<<<ngrid, 256, 0, stream>>>(h1, a_src1, a_dst1, als, ald, C_ONE);
    k_gather1<<<ngrid, 256, 0, stream>>>(rs, srcs, als, ald, h1, b1, out1b);

    // ---- layer 2 ----
    k_gemm2<<<(N_NODES + 127) / 128, 256, 0, stream>>>(out1b, W2t, h2);
    k_att_node<<<ngrid, 256, 0, stream>>>(h2, a_src2, a_dst2, als, ald, D_OUT);
    k_gather2<<<ngrid, 256, 0, stream>>>(rs, srcs, als, ald, h2, b2, out);
}

// Round 5
// 674.093 us; speedup vs baseline: 12.1695x; 1.3649x over previous
//
#include <hip/hip_runtime.h>
#include <math.h>

#define N_NODES 100000
#define D_IN    1000
#define D_OUT   20
#define N_HEAD  8
#define C_ONE   8
#define SCAN_CHUNK 512
#define NCH ((N_NODES + SCAN_CHUNK - 1) / SCAN_CHUNK)

// GEMM1 tiling
#define BM 128
#define BN 64
#define BK 64
#define KPAD 1024
#define KTILES 16

static constexpr float kBnEps = 1e-5f;
static constexpr float kSlope = 0.2f;

typedef __attribute__((ext_vector_type(8))) short short8;
typedef __attribute__((ext_vector_type(4))) short sh4;
typedef __attribute__((ext_vector_type(4))) float f32x4;

__device__ __forceinline__ unsigned short f2bf(float f) {
    unsigned u = __float_as_uint(f);
    unsigned r = (u + 0x7fffu + ((u >> 16) & 1u)) >> 16;  // RNE
    return (unsigned short)r;
}
__device__ __forceinline__ float bf2f(short s) {
    unsigned u = ((unsigned)(unsigned short)s) << 16;
    return __uint_as_float(u);
}

// ---- BN column stats: float4 columns per thread, 100-row chunks ----
__global__ __launch_bounds__(256) void k_bn_partial(const float* __restrict__ x,
                                                    float* __restrict__ cs,
                                                    float* __restrict__ cs2,
                                                    int rows_per_chunk) {
    int c4 = threadIdx.x;
    if (c4 >= 250) return;
    int r0 = blockIdx.x * rows_per_chunk;
    int r1 = min(r0 + rows_per_chunk, N_NODES);
    float sx = 0.f, sy = 0.f, sz = 0.f, sw = 0.f;
    float qx = 0.f, qy = 0.f, qz = 0.f, qw = 0.f;
    const char* base = (const char*)(x + (size_t)c4 * 4);
    #pragma unroll 4
    for (int i = r0; i < r1; ++i) {
        float4 v = *(const float4*)(base + (size_t)i * (D_IN * 4));
        sx += v.x; sy += v.y; sz += v.z; sw += v.w;
        qx += v.x * v.x; qy += v.y * v.y; qz += v.z * v.z; qw += v.w * v.w;
    }
    atomicAdd(&cs[c4 * 4 + 0], sx);
    atomicAdd(&cs[c4 * 4 + 1], sy);
    atomicAdd(&cs[c4 * 4 + 2], sz);
    atomicAdd(&cs[c4 * 4 + 3], sw);
    atomicAdd(&cs2[c4 * 4 + 0], qx);
    atomicAdd(&cs2[c4 * 4 + 1], qy);
    atomicAdd(&cs2[c4 * 4 + 2], qz);
    atomicAdd(&cs2[c4 * 4 + 3], qw);
}

__global__ void k_bn_finalize(const float* __restrict__ cs, const float* __restrict__ cs2,
                              const float* __restrict__ gamma, const float* __restrict__ beta,
                              float* __restrict__ scale, float* __restrict__ shift) {
    int k = blockIdx.x * blockDim.x + threadIdx.x;
    if (k >= D_IN) return;
    float mu  = cs[k]  * (1.f / N_NODES);
    float var = cs2[k] * (1.f / N_NODES) - mu * mu;
    float sc  = rsqrtf(var + kBnEps) * gamma[k];
    scale[k] = sc;
    shift[k] = beta[k] - mu * sc;
}

// W1t[n][k] = bf16(scale[k] * W1[k][n]), K zero-padded to 1024
__global__ void k_prep_w1t(const float* __restrict__ W1, const float* __restrict__ scale,
                           short* __restrict__ W1t) {
    int idx = blockIdx.x * blockDim.x + threadIdx.x;
    if (idx >= 64 * KPAD) return;
    int n = idx >> 10, k = idx & (KPAD - 1);
    float v = (k < D_IN) ? W1[k * 64 + n] * scale[k] : 0.f;
    W1t[idx] = (short)f2bf(v);
}

// W2t[n][k] = bf16(W2[k][n]);  W2 is [64][160]
__global__ void k_prep_w2t(const float* __restrict__ W2, short* __restrict__ W2t) {
    int idx = blockIdx.x * blockDim.x + threadIdx.x;
    if (idx >= 160 * 64) return;
    int n = idx >> 6, k = idx & 63;
    W2t[idx] = (short)f2bf(W2[k * 160 + n]);
}

// c1[j] = sum_k shift[k] * W1[k][j]  (f32, exact)
__global__ void k_prep_c1(const float* __restrict__ W1, const float* __restrict__ shift,
                          float* __restrict__ c1) {
    __shared__ float part[4][64];
    int j  = threadIdx.x & 63;
    int kc = threadIdx.x >> 6;
    float acc = 0.f;
    for (int k = kc * 250; k < (kc + 1) * 250; ++k)
        acc += shift[k] * W1[k * 64 + j];
    part[kc][j] = acc;
    __syncthreads();
    if (kc == 0) c1[j] = part[0][j] + part[1][j] + part[2][j] + part[3][j];
}

// ===== h1b(bf16) = bf16(x) @ W1t + c1 via MFMA; 128x64 tile, BK=64, swizzled LDS =====
__global__ __launch_bounds__(256) void k_gemm1(const float* __restrict__ x,
                                               const short* __restrict__ W1t,
                                               const float* __restrict__ c1,
                                               short* __restrict__ h1b) {
    __shared__ short lA[BM * BK];
    __shared__ short lB[BN * BK];

    int tid  = threadIdx.x;
    int lane = tid & 63;
    int wave = tid >> 6;
    int l15  = lane & 15, kq = lane >> 4;
    int row0 = blockIdx.x * BM;
    int wm0  = wave * 32;

    f32x4 zero4 = {0.f, 0.f, 0.f, 0.f};
    f32x4 acc[2][4];
    #pragma unroll
    for (int m = 0; m < 2; ++m)
        #pragma unroll
        for (int n = 0; n < 4; ++n) acc[m][n] = zero4;

    int ar = tid >> 4;
    int akf4 = tid & 15;

    for (int kt = 0; kt < KTILES; ++kt) {
        int k0 = kt * BK;
        bool kok = (k0 + akf4 * 4) < D_IN;
        #pragma unroll
        for (int p = 0; p < 8; ++p) {
            int r = ar + p * 16;
            int gr = row0 + r;
            float4 v = make_float4(0.f, 0.f, 0.f, 0.f);
            if (gr < N_NODES && kok)
                v = *(const float4*)(x + (size_t)gr * D_IN + k0 + akf4 * 4);
            unsigned lo = f2bf(v.x) | ((unsigned)f2bf(v.y) << 16);
            unsigned hi = f2bf(v.z) | ((unsigned)f2bf(v.w) << 16);
            int off = r * 128 + ((((akf4 >> 1) ^ (r & 7)) << 4) | ((akf4 & 1) << 3));
            *(uint2*)((char*)lA + off) = make_uint2(lo, hi);
        }
        #pragma unroll
        for (int c = tid; c < 512; c += 256) {
            int n = c >> 3, s = c & 7;
            short8 v = *(const short8*)((const char*)W1t + n * (KPAD * 2) + k0 * 2 + (s << 4));
            int off = n * 128 + ((s ^ (n & 7)) << 4);
            *(short8*)((char*)lB + off) = v;
        }
        __syncthreads();
        #pragma unroll
        for (int h = 0; h < 2; ++h) {
            short8 aF[2], bF[4];
            #pragma unroll
            for (int m = 0; m < 2; ++m) {
                int row = wm0 + m * 16 + l15;
                int off = row * 128 + (((((h << 2) + kq)) ^ (row & 7)) << 4);
                aF[m] = *(const short8*)((const char*)lA + off);
            }
            #pragma unroll
            for (int n = 0; n < 4; ++n) {
                int col = n * 16 + l15;
                int off = col * 128 + (((((h << 2) + kq)) ^ (col & 7)) << 4);
                bF[n] = *(const short8*)((const char*)lB + off);
            }
            #pragma unroll
            for (int m = 0; m < 2; ++m)
                #pragma unroll
                for (int n = 0; n < 4; ++n)
                    acc[m][n] = __builtin_amdgcn_mfma_f32_16x16x32_bf16(aF[m], bF[n], acc[m][n], 0, 0, 0);
        }
        __syncthreads();
    }

    // epilogue: +c1, bf16, transpose via lA, contiguous 16B stores
    float cv[4];
    #pragma unroll
    for (int n = 0; n < 4; ++n) cv[n] = c1[n * 16 + l15];
    #pragma unroll
    for (int m = 0; m < 2; ++m)
        #pragma unroll
        for (int q = 0; q < 4; ++q) {
            int rl = wm0 + m * 16 + (kq << 2) + q;
            #pragma unroll
            for (int n = 0; n < 4; ++n)
                lA[rl * 64 + n * 16 + l15] = (short)f2bf(acc[m][n][q] + cv[n]);
        }
    __syncthreads();
    #pragma unroll
    for (int idx = tid; idx < 1024; idx += 256) {
        int r = idx >> 3, s = idx & 7;
        int gr = row0 + r;
        if (gr < N_NODES)
            *(short8*)((char*)h1b + (size_t)gr * 128 + (s << 4)) =
                *(const short8*)((const char*)lA + r * 128 + (s << 4));
    }
}

// ===== h2b(bf16) = out1b @ W2t; 128x160 tile, K=64 =====
__global__ __launch_bounds__(256) void k_gemm2(const short* __restrict__ out1b,
                                               const short* __restrict__ W2t,
                                               short* __restrict__ h2b) {
    __shared__ __align__(16) char smem[40960];
    short* lA  = (short*)smem;            // 16 KB (128x64)
    short* lB  = (short*)(smem + 16384);  // 20 KB (160x64)
    short* stg = (short*)smem;            // 40 KB (128x160), reused after compute

    int tid  = threadIdx.x;
    int lane = tid & 63;
    int wave = tid >> 6;
    int l15  = lane & 15, kq = lane >> 4;
    int row0 = blockIdx.x * 128;
    int wm0  = wave * 32;

    #pragma unroll
    for (int p = 0; p < 4; ++p) {
        int idx = tid + p * 256;
        int r = idx >> 3, s = idx & 7;
        int gr = row0 + r;
        short8 v = {};
        if (gr < N_NODES)
            v = *(const short8*)((const char*)out1b + (size_t)gr * 128 + (s << 4));
        int off = r * 128 + ((s ^ (r & 7)) << 4);
        *(short8*)((char*)lA + off) = v;
    }
    #pragma unroll
    for (int p = 0; p < 5; ++p) {
        int idx = tid + p * 256;
        int n = idx >> 3, s = idx & 7;
        short8 v = *(const short8*)((const char*)W2t + n * 128 + (s << 4));
        int off = n * 128 + ((s ^ (n & 7)) << 4);
        *(short8*)((char*)lB + off) = v;
    }
    __syncthreads();

    f32x4 zero4 = {0.f, 0.f, 0.f, 0.f};
    f32x4 acc[2][10];
    #pragma unroll
    for (int m = 0; m < 2; ++m)
        #pragma unroll
        for (int n = 0; n < 10; ++n) acc[m][n] = zero4;

    #pragma unroll
    for (int h = 0; h < 2; ++h) {
        short8 aF[2], bF[10];
        #pragma unroll
        for (int m = 0; m < 2; ++m) {
            int row = wm0 + m * 16 + l15;
            int off = row * 128 + ((((h << 2) + kq) ^ (row & 7)) << 4);
            aF[m] = *(const short8*)((const char*)lA + off);
        }
        #pragma unroll
        for (int n = 0; n < 10; ++n) {
            int col = n * 16 + l15;
            int off = col * 128 + ((((h << 2) + kq) ^ (col & 7)) << 4);
            bF[n] = *(const short8*)((const char*)lB + off);
        }
        #pragma unroll
        for (int m = 0; m < 2; ++m)
            #pragma unroll
            for (int n = 0; n < 10; ++n)
                acc[m][n] = __builtin_amdgcn_mfma_f32_16x16x32_bf16(aF[m], bF[n], acc[m][n], 0, 0, 0);
    }

    __syncthreads();  // all fragment reads done; reuse smem as stage
    #pragma unroll
    for (int m = 0; m < 2; ++m)
        #pragma unroll
        for (int q = 0; q < 4; ++q) {
            int rl = wm0 + m * 16 + (kq << 2) + q;
            #pragma unroll
            for (int n = 0; n < 10; ++n)
                stg[rl * 160 + n * 16 + l15] = (short)f2bf(acc[m][n][q]);
        }
    __syncthreads();
    #pragma unroll
    for (int p = 0; p < 10; ++p) {
        int idx = tid + p * 256;
        int r = idx / 20, c8 = idx % 20;
        int gr = row0 + r;
        if (gr < N_NODES)
            *(short8*)((char*)h2b + (size_t)gr * 320 + (c8 << 4)) =
                *(const short8*)((const char*)stg + r * 320 + (c8 << 4));
    }
}

// attention logits per node, layer1 (C=8, bf16 h)
__global__ void k_att_node1(const short* __restrict__ h, const float* __restrict__ a_src,
                            const float* __restrict__ a_dst, float* __restrict__ als,
                            float* __restrict__ ald) {
    int idx = blockIdx.x * blockDim.x + threadIdx.x;
    if (idx >= N_NODES * N_HEAD) return;
    int i = idx >> 3, hd = idx & 7;
    short8 v = *(const short8*)((const char*)h + (size_t)i * 128 + hd * 16);
    const float* as = a_src + hd * 8;
    const float* ad = a_dst + hd * 8;
    float s = 0.f, d = 0.f;
    #pragma unroll
    for (int c = 0; c < 8; ++c) {
        float f = bf2f(v[c]);
        s += f * as[c];
        d += f * ad[c];
    }
    als[idx] = s;
    ald[idx] = d;
}

// attention logits per node, layer2 (C=20, bf16 h)
__global__ void k_att_node2(const short* __restrict__ h, const float* __restrict__ a_src,
                            const float* __restrict__ a_dst, float* __restrict__ als,
                            float* __restrict__ ald) {
    int idx = blockIdx.x * blockDim.x + threadIdx.x;
    if (idx >= N_NODES * N_HEAD) return;
    int i = idx >> 3, hd = idx & 7;
    const char* hp = (const char*)h + (size_t)i * 320 + hd * 40;
    const float* as = a_src + hd * 20;
    const float* ad = a_dst + hd * 20;
    float s = 0.f, d = 0.f;
    #pragma unroll
    for (int p = 0; p < 5; ++p) {
        sh4 v = *(const sh4*)(hp + p * 8);
        #pragma unroll
        for (int j = 0; j < 4; ++j) {
            float f = bf2f(v[j]);
            s += f * as[p * 4 + j];
            d += f * ad[p * 4 + j];
        }
    }
    als[idx] = s;
    ald[idx] = d;
}

// ============ CSR build ============
__global__ void k_deg(const int* __restrict__ ei, int E, int TE, int* __restrict__ deg) {
    int eid = blockIdx.x * blockDim.x + threadIdx.x;
    if (eid >= TE) return;
    int dst = (eid < E) ? ei[E + eid] : (eid - E);
    atomicAdd(&deg[dst], 1);
}

__global__ void k_scan_a(const int* __restrict__ deg, int* __restrict__ csum) {
    __shared__ int red[4];
    int c = blockIdx.x, tid = threadIdx.x;
    int i0 = c * SCAN_CHUNK + tid * 2;
    int a = (i0 < N_NODES) ? deg[i0] : 0;
    int b = (i0 + 1 < N_NODES) ? deg[i0 + 1] : 0;
    int t = a + b;
    #pragma unroll
    for (int d = 1; d < 64; d <<= 1) t += __shfl_xor(t, d);
    if ((tid & 63) == 0) red[tid >> 6] = t;
    __syncthreads();
    if (tid == 0) csum[c] = red[0] + red[1] + red[2] + red[3];
}

__global__ void k_scan_b(int* __restrict__ csum, int total, int* __restrict__ row_start) {
    if (threadIdx.x == 0) {
        int acc = 0;
        for (int i = 0; i < NCH; ++i) { int v = csum[i]; csum[i] = acc; acc += v; }
        row_start[N_NODES] = total;
    }
}

__global__ void k_scan_c(const int* __restrict__ deg, const int* __restrict__ csum,
                         int* __restrict__ row_start, int* __restrict__ cursor) {
    __shared__ int wsum[4];
    int c = blockIdx.x, tid = threadIdx.x;
    int lane = tid & 63, w = tid >> 6;
    int i0 = c * SCAN_CHUNK + tid * 2;
    int a = (i0 < N_NODES) ? deg[i0] : 0;
    int b = (i0 + 1 < N_NODES) ? deg[i0 + 1] : 0;
    int t = a + b;
    int incl = t;
    #pragma unroll
    for (int d = 1; d < 64; d <<= 1) {
        int v = __shfl_up(incl, d);
        if (lane >= d) incl += v;
    }
    if (lane == 63) wsum[w] = incl;
    __syncthreads();
    int wbase = 0;
    for (int k = 0; k < w; ++k) wbase += wsum[k];
    int ex = csum[c] + wbase + incl - t;
    if (i0 < N_NODES)     { row_start[i0] = ex;         cursor[i0] = ex; }
    if (i0 + 1 < N_NODES) { row_start[i0 + 1] = ex + a; cursor[i0 + 1] = ex + a; }
}

__global__ void k_fill(const int* __restrict__ ei, int E, int TE,
                       int* __restrict__ cursor, int* __restrict__ srcs) {
    int eid = blockIdx.x * blockDim.x + threadIdx.x;
    if (eid >= TE) return;
    int src, dst;
    if (eid < E) { src = ei[eid]; dst = ei[E + eid]; }
    else { src = eid - E; dst = src; }
    int pos = atomicAdd(&cursor[dst], 1);
    srcs[pos] = src;
}

// ====== layer-1 gather: single-pass online softmax + bias + ELU -> bf16 out1 ======
__global__ __launch_bounds__(256) void k_gather1(const int* __restrict__ row_start,
                                                 const int* __restrict__ srcs,
                                                 const float* __restrict__ als,
                                                 const float* __restrict__ ald,
                                                 const short* __restrict__ h,
                                                 const float* __restrict__ b1,
                                                 short* __restrict__ out1b) {
    int idx = blockIdx.x * blockDim.x + threadIdx.x;
    if (idx >= N_NODES * N_HEAD) return;
    int dst = idx >> 3, hd = idx & 7;
    int beg = row_start[dst], end = row_start[dst + 1];
    float ad = ald[idx];
    float m = -1e30f, sum = 0.f;
    float acc[C_ONE] = {};
    for (int e = beg; e < end; ++e) {
        int s = srcs[e];
        float v = als[s * N_HEAD + hd] + ad;
        v = v >= 0.f ? v : kSlope * v;
        short8 hv = *(const short8*)((const char*)h + (size_t)s * 128 + hd * 16);
        if (v <= m) {
            float w = expf(v - m);
            sum += w;
            #pragma unroll
            for (int c = 0; c < C_ONE; ++c) acc[c] += w * bf2f(hv[c]);
        } else {
            float r = expf(m - v);
            sum = sum * r + 1.f;
            #pragma unroll
            for (int c = 0; c < C_ONE; ++c) acc[c] = acc[c] * r + bf2f(hv[c]);
            m = v;
        }
    }
    float inv = 1.f / (sum + 1e-16f);
    short8 o;
    #pragma unroll
    for (int c = 0; c < C_ONE; ++c) {
        float v = acc[c] * inv + b1[hd * C_ONE + c];
        v = v > 0.f ? v : expf(v) - 1.f;
        o[c] = (short)f2bf(v);
    }
    *(short8*)((char*)out1b + (size_t)dst * 128 + hd * 16) = o;
}

// ====== layer-2 gather: single-pass online softmax + head-mean + bias + log_softmax ======
__global__ __launch_bounds__(256) void k_gather2(const int* __restrict__ row_start,
                                                 const int* __restrict__ srcs,
                                                 const float* __restrict__ als,
                                                 const float* __restrict__ ald,
                                                 const short* __restrict__ h2,
                                                 const float* __restrict__ b2,
                                                 float* __restrict__ out) {
    int idx = blockIdx.x * blockDim.x + threadIdx.x;
    if (idx >= N_NODES * N_HEAD) return;
    int dst = idx >> 3, hd = idx & 7;
    int beg = row_start[dst], end = row_start[dst + 1];
    float ad = ald[idx];
    float m = -1e30f, sum = 0.f;
    float acc[D_OUT] = {};
    for (int e = beg; e < end; ++e) {
        int s = srcs[e];
        float v = als[s * N_HEAD + hd] + ad;
        v = v >= 0.f ? v : kSlope * v;
        const char* hp = (const char*)h2 + (size_t)s * 320 + hd * 40;
        float hv[D_OUT];
        #pragma unroll
        for (int p = 0; p < 5; ++p) {
            sh4 t = *(const sh4*)(hp + p * 8);
            #pragma unroll
            for (int j = 0; j < 4; ++j) hv[p * 4 + j] = bf2f(t[j]);
        }
        if (v <= m) {
            float w = expf(v - m);
            sum += w;
            #pragma unroll
            for (int c = 0; c < D_OUT; ++c) acc[c] += w * hv[c];
        } else {
            float r = expf(m - v);
            sum = sum * r + 1.f;
            #pragma unroll
            for (int c = 0; c < D_OUT; ++c) acc[c] = acc[c] * r + hv[c];
            m = v;
        }
    }
    float inv = 1.f / (sum + 1e-16f);
    #pragma unroll
    for (int c = 0; c < D_OUT; ++c) {
        float v = acc[c] * inv;
        v += __shfl_xor(v, 1);
        v += __shfl_xor(v, 2);
        v += __shfl_xor(v, 4);
        acc[c] = v;
    }
    if (hd == 0) {
        float vals[D_OUT];
        float mx = -1e30f;
        #pragma unroll
        for (int c = 0; c < D_OUT; ++c) {
            vals[c] = 0.125f * acc[c] + b2[c];
            mx = fmaxf(mx, vals[c]);
        }
        float s = 0.f;
        #pragma unroll
        for (int c = 0; c < D_OUT; ++c) s += expf(vals[c] - mx);
        float lse = mx + logf(s);
        float* op = out + (size_t)dst * D_OUT;
        #pragma unroll
        for (int c = 0; c < D_OUT; ++c) op[c] = vals[c] - lse;
    }
}

extern "C" void kernel_launch(void* const* d_in, const int* in_sizes, int n_in,
                              void* d_out, int out_size, void* d_ws, size_t ws_size,
                              hipStream_t stream) {
    const float* x      = (const float*)d_in[0];
    const int*   ei     = (const int*)d_in[1];
    const float* gamma  = (const float*)d_in[2];
    const float* beta   = (const float*)d_in[3];
    const float* W1     = (const float*)d_in[4];
    const float* a_src1 = (const float*)d_in[5];
    const float* a_dst1 = (const float*)d_in[6];
    const float* b1     = (const float*)d_in[7];
    const float* W2     = (const float*)d_in[8];
    const float* a_src2 = (const float*)d_in[9];
    const float* a_dst2 = (const float*)d_in[10];
    const float* b2     = (const float*)d_in[11];
    float* out = (float*)d_out;
    (void)n_in; (void)out_size; (void)ws_size;

    const int E  = in_sizes[1] / 2;
    const int TE = E + N_NODES;

    char* wsb = (char*)d_ws;
    size_t off = 0;
    auto alloc = [&](size_t bytes) -> void* {
        void* p = wsb + off;
        off += (bytes + 255) & ~(size_t)255;
        return p;
    };
    float* cs    = (float*)alloc(D_IN * sizeof(float));
    float* cs2   = (float*)alloc(D_IN * sizeof(float));
    float* scale = (float*)alloc(D_IN * sizeof(float));
    float* shift = (float*)alloc(D_IN * sizeof(float));
    short* W1t   = (short*)alloc((size_t)64 * KPAD * sizeof(short));
    short* W2t   = (short*)alloc((size_t)160 * 64 * sizeof(short));
    float* c1    = (float*)alloc(64 * sizeof(float));
    short* h1b   = (short*)alloc((size_t)N_NODES * 64 * sizeof(short));
    short* h2b   = (short*)alloc((size_t)N_NODES * 160 * sizeof(short));
    float* als   = (float*)alloc((size_t)N_NODES * N_HEAD * sizeof(float));
    float* ald   = (float*)alloc((size_t)N_NODES * N_HEAD * sizeof(float));
    short* out1b = (short*)alloc((size_t)N_NODES * 64 * sizeof(short));
    int*   deg   = (int*)alloc((size_t)N_NODES * sizeof(int));
    int*   rs    = (int*)alloc((size_t)(N_NODES + 1) * sizeof(int));
    int*   cur   = (int*)alloc((size_t)N_NODES * sizeof(int));
    int*   csum  = (int*)alloc((size_t)NCH * sizeof(int));
    int*   srcs  = (int*)alloc((size_t)TE * sizeof(int));

    int egrid = (TE + 255) / 256;
    int ngrid = (N_NODES * N_HEAD) / 256;

    // ---- CSR build ----
    hipMemsetAsync(deg, 0, (size_t)N_NODES * sizeof(int), stream);
    k_deg<<<egrid, 256, 0, stream>>>(ei, E, TE, deg);
    k_scan_a<<<NCH, 256, 0, stream>>>(deg, csum);
    k_scan_b<<<1, 64, 0, stream>>>(csum, TE, rs);
    k_scan_c<<<NCH, 256, 0, stream>>>(deg, csum, rs, cur);
    k_fill<<<egrid, 256, 0, stream>>>(ei, E, TE, cur, srcs);

    // ---- BN stats + weight folding ----
    hipMemsetAsync(cs, 0, D_IN * sizeof(float), stream);
    hipMemsetAsync(cs2, 0, D_IN * sizeof(float), stream);
    k_bn_partial<<<1000, 256, 0, stream>>>(x, cs, cs2, 100);
    k_bn_finalize<<<(D_IN + 255) / 256, 256, 0, stream>>>(cs, cs2, gamma, beta, scale, shift);
    k_prep_w1t<<<(64 * KPAD) / 256, 256, 0, stream>>>(W1, scale, W1t);
    k_prep_w2t<<<(160 * 64) / 256, 256, 0, stream>>>(W2, W2t);
    k_prep_c1<<<1, 256, 0, stream>>>(W1, shift, c1);

    // ---- layer 1 ----
    k_gemm1<<<(N_NODES + BM - 1) / BM, 256, 0, stream>>>(x, W1t, c1, h1b);
    k_att_node1<<<ngrid, 256, 0, stream>>>(h1b, a_src1, a_dst1, als, ald);
    k_gather1<<<ngrid, 256, 0, stream>>>(rs, srcs, als, ald, h1b, b1, out1b);

    // ---- layer 2 ----
    k_gemm2<<<(N_NODES + 127) / 128, 256, 0, stream>>>(out1b, W2t, h2b);
    k_att_node2<<<ngrid, 256, 0, stream>>>(h2b, a_src2, a_dst2, als, ald);
    k_gather2<<<ngrid, 256, 0, stream>>>(rs, srcs, als, ald, h2b, b2, out);
}

// Round 6
// 649.264 us; speedup vs baseline: 12.6348x; 1.0382x over previous
//
#include <hip/hip_runtime.h>
#include <math.h>

#define N_NODES 100000
#define D_IN    1000
#define D_OUT   20
#define N_HEAD  8
#define C_ONE   8
#define SCAN_CHUNK 512
#define NCH ((N_NODES + SCAN_CHUNK - 1) / SCAN_CHUNK)

// GEMM1 tiling
#define BM 128
#define BN 64
#define BK 64
#define KPAD 1024
#define KTILES 16

static constexpr float kBnEps = 1e-5f;
static constexpr float kSlope = 0.2f;

typedef __attribute__((ext_vector_type(8))) short short8;
typedef __attribute__((ext_vector_type(4))) short sh4;
typedef __attribute__((ext_vector_type(4))) float f32x4;

__device__ __forceinline__ unsigned short f2bf(float f) {
    unsigned u = __float_as_uint(f);
    unsigned r = (u + 0x7fffu + ((u >> 16) & 1u)) >> 16;  // RNE
    return (unsigned short)r;
}
__device__ __forceinline__ float bf2f(short s) {
    unsigned u = ((unsigned)(unsigned short)s) << 16;
    return __uint_as_float(u);
}

// ---- BN column stats: float4 columns per thread, 100-row chunks ----
__global__ __launch_bounds__(256) void k_bn_partial(const float* __restrict__ x,
                                                    float* __restrict__ cs,
                                                    float* __restrict__ cs2,
                                                    int rows_per_chunk) {
    int c4 = threadIdx.x;
    if (c4 >= 250) return;
    int r0 = blockIdx.x * rows_per_chunk;
    int r1 = min(r0 + rows_per_chunk, N_NODES);
    float sx = 0.f, sy = 0.f, sz = 0.f, sw = 0.f;
    float qx = 0.f, qy = 0.f, qz = 0.f, qw = 0.f;
    const char* base = (const char*)(x + (size_t)c4 * 4);
    #pragma unroll 4
    for (int i = r0; i < r1; ++i) {
        float4 v = *(const float4*)(base + (size_t)i * (D_IN * 4));
        sx += v.x; sy += v.y; sz += v.z; sw += v.w;
        qx += v.x * v.x; qy += v.y * v.y; qz += v.z * v.z; qw += v.w * v.w;
    }
    atomicAdd(&cs[c4 * 4 + 0], sx);
    atomicAdd(&cs[c4 * 4 + 1], sy);
    atomicAdd(&cs[c4 * 4 + 2], sz);
    atomicAdd(&cs[c4 * 4 + 3], sw);
    atomicAdd(&cs2[c4 * 4 + 0], qx);
    atomicAdd(&cs2[c4 * 4 + 1], qy);
    atomicAdd(&cs2[c4 * 4 + 2], qz);
    atomicAdd(&cs2[c4 * 4 + 3], qw);
}

__global__ void k_bn_finalize(const float* __restrict__ cs, const float* __restrict__ cs2,
                              const float* __restrict__ gamma, const float* __restrict__ beta,
                              float* __restrict__ scale, float* __restrict__ shift) {
    int k = blockIdx.x * blockDim.x + threadIdx.x;
    if (k >= D_IN) return;
    float mu  = cs[k]  * (1.f / N_NODES);
    float var = cs2[k] * (1.f / N_NODES) - mu * mu;
    float sc  = rsqrtf(var + kBnEps) * gamma[k];
    scale[k] = sc;
    shift[k] = beta[k] - mu * sc;
}

// merged weight prep: blocks [0,256) -> W1t, [256,296) -> W2t, 296 -> c1
__global__ void k_prep(const float* __restrict__ W1, const float* __restrict__ W2,
                       const float* __restrict__ scale, const float* __restrict__ shift,
                       short* __restrict__ W1t, short* __restrict__ W2t,
                       float* __restrict__ c1) {
    __shared__ float part[4][64];
    int b = blockIdx.x, tid = threadIdx.x;
    if (b < 256) {
        int idx = b * 256 + tid;                  // 64*KPAD = 65536
        int n = idx >> 10, k = idx & (KPAD - 1);
        float v = (k < D_IN) ? W1[k * 64 + n] * scale[k] : 0.f;
        W1t[idx] = (short)f2bf(v);
    } else if (b < 296) {
        int idx = (b - 256) * 256 + tid;          // 160*64 = 10240
        if (idx < 160 * 64) {
            int n = idx >> 6, k = idx & 63;
            W2t[idx] = (short)f2bf(W2[k * 160 + n]);
        }
    } else {
        int j  = tid & 63;
        int kc = tid >> 6;
        float acc = 0.f;
        for (int k = kc * 250; k < (kc + 1) * 250; ++k)
            acc += shift[k] * W1[k * 64 + j];
        part[kc][j] = acc;
        __syncthreads();
        if (kc == 0) c1[j] = part[0][j] + part[1][j] + part[2][j] + part[3][j];
    }
}

// ===== h1b(bf16) = bf16(x) @ W1t + c1 via MFMA; fused att1 logits in epilogue =====
__global__ __launch_bounds__(256) void k_gemm1(const float* __restrict__ x,
                                               const short* __restrict__ W1t,
                                               const float* __restrict__ c1,
                                               const float* __restrict__ a_src1,
                                               const float* __restrict__ a_dst1,
                                               short* __restrict__ h1b,
                                               float* __restrict__ als,
                                               float* __restrict__ ald) {
    __shared__ short lA[BM * BK];
    __shared__ short lB[BN * BK];

    int tid  = threadIdx.x;
    int lane = tid & 63;
    int wave = tid >> 6;
    int l15  = lane & 15, kq = lane >> 4;
    int row0 = blockIdx.x * BM;
    int wm0  = wave * 32;

    f32x4 zero4 = {0.f, 0.f, 0.f, 0.f};
    f32x4 acc[2][4];
    #pragma unroll
    for (int m = 0; m < 2; ++m)
        #pragma unroll
        for (int n = 0; n < 4; ++n) acc[m][n] = zero4;

    int ar = tid >> 4;
    int akf4 = tid & 15;

    for (int kt = 0; kt < KTILES; ++kt) {
        int k0 = kt * BK;
        bool kok = (k0 + akf4 * 4) < D_IN;
        #pragma unroll
        for (int p = 0; p < 8; ++p) {
            int r = ar + p * 16;
            int gr = row0 + r;
            float4 v = make_float4(0.f, 0.f, 0.f, 0.f);
            if (gr < N_NODES && kok)
                v = *(const float4*)(x + (size_t)gr * D_IN + k0 + akf4 * 4);
            unsigned lo = f2bf(v.x) | ((unsigned)f2bf(v.y) << 16);
            unsigned hi = f2bf(v.z) | ((unsigned)f2bf(v.w) << 16);
            int off = r * 128 + ((((akf4 >> 1) ^ (r & 7)) << 4) | ((akf4 & 1) << 3));
            *(uint2*)((char*)lA + off) = make_uint2(lo, hi);
        }
        #pragma unroll
        for (int c = tid; c < 512; c += 256) {
            int n = c >> 3, s = c & 7;
            short8 v = *(const short8*)((const char*)W1t + n * (KPAD * 2) + k0 * 2 + (s << 4));
            int off = n * 128 + ((s ^ (n & 7)) << 4);
            *(short8*)((char*)lB + off) = v;
        }
        __syncthreads();
        #pragma unroll
        for (int h = 0; h < 2; ++h) {
            short8 aF[2], bF[4];
            #pragma unroll
            for (int m = 0; m < 2; ++m) {
                int row = wm0 + m * 16 + l15;
                int off = row * 128 + (((((h << 2) + kq)) ^ (row & 7)) << 4);
                aF[m] = *(const short8*)((const char*)lA + off);
            }
            #pragma unroll
            for (int n = 0; n < 4; ++n) {
                int col = n * 16 + l15;
                int off = col * 128 + (((((h << 2) + kq)) ^ (col & 7)) << 4);
                bF[n] = *(const short8*)((const char*)lB + off);
            }
            #pragma unroll
            for (int m = 0; m < 2; ++m)
                #pragma unroll
                for (int n = 0; n < 4; ++n)
                    acc[m][n] = __builtin_amdgcn_mfma_f32_16x16x32_bf16(aF[m], bF[n], acc[m][n], 0, 0, 0);
        }
        __syncthreads();
    }

    // epilogue: +c1, bf16, linear [128][64] in lA
    float cv[4];
    #pragma unroll
    for (int n = 0; n < 4; ++n) cv[n] = c1[n * 16 + l15];
    #pragma unroll
    for (int m = 0; m < 2; ++m)
        #pragma unroll
        for (int q = 0; q < 4; ++q) {
            int rl = wm0 + m * 16 + (kq << 2) + q;
            #pragma unroll
            for (int n = 0; n < 4; ++n)
                lA[rl * 64 + n * 16 + l15] = (short)f2bf(acc[m][n][q] + cv[n]);
        }
    __syncthreads();
    // h1b store
    #pragma unroll
    for (int idx = tid; idx < 1024; idx += 256) {
        int r = idx >> 3, s = idx & 7;
        int gr = row0 + r;
        if (gr < N_NODES)
            *(short8*)((char*)h1b + (size_t)gr * 128 + (s << 4)) =
                *(const short8*)((const char*)lA + r * 128 + (s << 4));
    }
    // fused att1 logits
    #pragma unroll
    for (int pair = tid; pair < 1024; pair += 256) {
        int r = pair >> 3, hd = pair & 7;
        int gr = row0 + r;
        if (gr >= N_NODES) continue;
        short8 v = *(const short8*)((const char*)lA + r * 128 + hd * 16);
        float s = 0.f, d = 0.f;
        #pragma unroll
        for (int c = 0; c < 8; ++c) {
            float f = bf2f(v[c]);
            s += f * a_src1[hd * 8 + c];
            d += f * a_dst1[hd * 8 + c];
        }
        als[gr * 8 + hd] = s;
        ald[gr * 8 + hd] = d;
    }
}

// ============ CSR build ============
__global__ void k_deg(const int* __restrict__ ei, int E, int TE, int* __restrict__ deg) {
    int eid = blockIdx.x * blockDim.x + threadIdx.x;
    if (eid >= TE) return;
    int dst = (eid < E) ? ei[E + eid] : (eid - E);
    atomicAdd(&deg[dst], 1);
}

__global__ void k_scan_a(const int* __restrict__ deg, int* __restrict__ csum) {
    __shared__ int red[4];
    int c = blockIdx.x, tid = threadIdx.x;
    int i0 = c * SCAN_CHUNK + tid * 2;
    int a = (i0 < N_NODES) ? deg[i0] : 0;
    int b = (i0 + 1 < N_NODES) ? deg[i0 + 1] : 0;
    int t = a + b;
    #pragma unroll
    for (int d = 1; d < 64; d <<= 1) t += __shfl_xor(t, d);
    if ((tid & 63) == 0) red[tid >> 6] = t;
    __syncthreads();
    if (tid == 0) csum[c] = red[0] + red[1] + red[2] + red[3];
}

__global__ void k_scan_b(int* __restrict__ csum, int total, int* __restrict__ row_start) {
    if (threadIdx.x == 0) {
        int acc = 0;
        for (int i = 0; i < NCH; ++i) { int v = csum[i]; csum[i] = acc; acc += v; }
        row_start[N_NODES] = total;
    }
}

__global__ void k_scan_c(const int* __restrict__ deg, const int* __restrict__ csum,
                         int* __restrict__ row_start, int* __restrict__ cursor) {
    __shared__ int wsum[4];
    int c = blockIdx.x, tid = threadIdx.x;
    int lane = tid & 63, w = tid >> 6;
    int i0 = c * SCAN_CHUNK + tid * 2;
    int a = (i0 < N_NODES) ? deg[i0] : 0;
    int b = (i0 + 1 < N_NODES) ? deg[i0 + 1] : 0;
    int t = a + b;
    int incl = t;
    #pragma unroll
    for (int d = 1; d < 64; d <<= 1) {
        int v = __shfl_up(incl, d);
        if (lane >= d) incl += v;
    }
    if (lane == 63) wsum[w] = incl;
    __syncthreads();
    int wbase = 0;
    for (int k = 0; k < w; ++k) wbase += wsum[k];
    int ex = csum[c] + wbase + incl - t;
    if (i0 < N_NODES)     { row_start[i0] = ex;         cursor[i0] = ex; }
    if (i0 + 1 < N_NODES) { row_start[i0 + 1] = ex + a; cursor[i0 + 1] = ex + a; }
}

__global__ void k_fill(const int* __restrict__ ei, int E, int TE,
                       int* __restrict__ cursor, int* __restrict__ srcs) {
    int eid = blockIdx.x * blockDim.x + threadIdx.x;
    if (eid >= TE) return;
    int src, dst;
    if (eid < E) { src = ei[eid]; dst = ei[E + eid]; }
    else { src = eid - E; dst = src; }
    int pos = atomicAdd(&cursor[dst], 1);
    srcs[pos] = src;
}

// ====== FUSED layer-2 front: gather1 -> LDS -> gemm2 -> att2 logits, h2b out ======
// 512 threads, 128 dst rows per block
__global__ __launch_bounds__(512) void k_fused_l2(const int* __restrict__ row_start,
                                                  const int* __restrict__ srcs,
                                                  const float* __restrict__ als1,
                                                  const float* __restrict__ ald1,
                                                  const short* __restrict__ h1b,
                                                  const float* __restrict__ b1,
                                                  const short* __restrict__ W2t,
                                                  const float* __restrict__ a_src2,
                                                  const float* __restrict__ a_dst2,
                                                  short* __restrict__ h2b,
                                                  float* __restrict__ als2,
                                                  float* __restrict__ ald2) {
    __shared__ __align__(16) char smem[40960];
    short* lA  = (short*)smem;            // [128][64] swizzled bf16 out1 tile (16 KB)
    short* lB  = (short*)(smem + 16384);  // [160][64] swizzled W2t (20 KB)
    short* stg = (short*)smem;            // [128][160] bf16 h2 tile (40 KB), reused

    int tid  = threadIdx.x;
    int lane = tid & 63;
    int wave = tid >> 6;
    int l15  = lane & 15, kq = lane >> 4;
    int row0 = blockIdx.x * 128;
    int wm0  = wave * 16;

    // stage W2t (1280 16B-chunks)
    for (int idx = tid; idx < 1280; idx += 512) {
        int n = idx >> 3, s = idx & 7;
        short8 v = *(const short8*)((const char*)W2t + n * 128 + (s << 4));
        int off = n * 128 + ((s ^ (n & 7)) << 4);
        *(short8*)((char*)lB + off) = v;
    }

    // gather phase: 1024 (row,head) pairs, 2 per thread
    #pragma unroll
    for (int pp = 0; pp < 2; ++pp) {
        int pair = tid + pp * 512;
        int r = pair >> 3, hd = pair & 7;
        int dst = row0 + r;
        short8 o = {0, 0, 0, 0, 0, 0, 0, 0};
        if (dst < N_NODES) {
            int beg = row_start[dst], end = row_start[dst + 1];
            float ad = ald1[dst * 8 + hd];
            float m = -1e30f, sum = 0.f;
            float acc[C_ONE] = {};
            for (int e = beg; e < end; ++e) {
                int s = srcs[e];
                float v = als1[s * 8 + hd] + ad;
                v = v >= 0.f ? v : kSlope * v;
                short8 hv = *(const short8*)((const char*)h1b + (size_t)s * 128 + hd * 16);
                if (v <= m) {
                    float w = expf(v - m);
                    sum += w;
                    #pragma unroll
                    for (int c = 0; c < C_ONE; ++c) acc[c] += w * bf2f(hv[c]);
                } else {
                    float rr = expf(m - v);
                    sum = sum * rr + 1.f;
                    #pragma unroll
                    for (int c = 0; c < C_ONE; ++c) acc[c] = acc[c] * rr + bf2f(hv[c]);
                    m = v;
                }
            }
            float inv = 1.f / (sum + 1e-16f);
            #pragma unroll
            for (int c = 0; c < C_ONE; ++c) {
                float v = acc[c] * inv + b1[hd * 8 + c];
                v = v > 0.f ? v : expf(v) - 1.f;
                o[c] = (short)f2bf(v);
            }
        }
        int off = r * 128 + ((hd ^ (r & 7)) << 4);
        *(short8*)((char*)lA + off) = o;
    }
    __syncthreads();

    // MFMA: each of 8 waves does 16 rows x 160 cols
    f32x4 zero4 = {0.f, 0.f, 0.f, 0.f};
    f32x4 acc2[10];
    #pragma unroll
    for (int n = 0; n < 10; ++n) acc2[n] = zero4;

    #pragma unroll
    for (int hh = 0; hh < 2; ++hh) {
        short8 aF, bF[10];
        {
            int row = wm0 + l15;
            int off = row * 128 + ((((hh << 2) + kq) ^ (row & 7)) << 4);
            aF = *(const short8*)((const char*)lA + off);
        }
        #pragma unroll
        for (int n = 0; n < 10; ++n) {
            int col = n * 16 + l15;
            int off = col * 128 + ((((hh << 2) + kq) ^ (col & 7)) << 4);
            bF[n] = *(const short8*)((const char*)lB + off);
        }
        #pragma unroll
        for (int n = 0; n < 10; ++n)
            acc2[n] = __builtin_amdgcn_mfma_f32_16x16x32_bf16(aF, bF[n], acc2[n], 0, 0, 0);
    }
    __syncthreads();  // lA/lB reads done; reuse smem as stg

    #pragma unroll
    for (int q = 0; q < 4; ++q) {
        int rl = wm0 + (kq << 2) + q;
        #pragma unroll
        for (int n = 0; n < 10; ++n)
            stg[rl * 160 + n * 16 + l15] = (short)f2bf(acc2[n][q]);
    }
    __syncthreads();

    // att2 logits from stg
    for (int pair = tid; pair < 1024; pair += 512) {
        int r = pair >> 3, hd = pair & 7;
        int dst = row0 + r;
        if (dst >= N_NODES) continue;
        const char* hp = (const char*)stg + r * 320 + hd * 40;
        float s = 0.f, d = 0.f;
        #pragma unroll
        for (int p = 0; p < 5; ++p) {
            sh4 v = *(const sh4*)(hp + p * 8);
            #pragma unroll
            for (int j = 0; j < 4; ++j) {
                float f = bf2f(v[j]);
                s += f * a_src2[hd * 20 + p * 4 + j];
                d += f * a_dst2[hd * 20 + p * 4 + j];
            }
        }
        als2[dst * 8 + hd] = s;
        ald2[dst * 8 + hd] = d;
    }
    // h2b store (2560 16B-chunks)
    for (int idx = tid; idx < 2560; idx += 512) {
        int r = idx / 20, c8 = idx % 20;
        int gr = row0 + r;
        if (gr < N_NODES)
            *(short8*)((char*)h2b + (size_t)gr * 320 + (c8 << 4)) =
                *(const short8*)((const char*)stg + r * 320 + (c8 << 4));
    }
}

// ====== layer-2 gather: 2-way edge split, online softmax, head-mean, log_softmax ======
__global__ __launch_bounds__(256) void k_gather2(const int* __restrict__ row_start,
                                                 const int* __restrict__ srcs,
                                                 const float* __restrict__ als,
                                                 const float* __restrict__ ald,
                                                 const short* __restrict__ h2,
                                                 const float* __restrict__ b2,
                                                 float* __restrict__ out) {
    int idx = blockIdx.x * blockDim.x + threadIdx.x;
    if (idx >= N_NODES * 16) return;
    int dst  = idx >> 4;
    int sub  = idx & 15;
    int hd   = sub >> 1;
    int half = sub & 1;
    int beg0 = row_start[dst], end0 = row_start[dst + 1];
    int mid  = beg0 + ((end0 - beg0 + 1) >> 1);
    int beg  = half ? mid : beg0;
    int end  = half ? end0 : mid;
    float ad = ald[dst * 8 + hd];
    float m = -1e30f, sum = 0.f;
    float acc[D_OUT] = {};
    for (int e = beg; e < end; ++e) {
        int s = srcs[e];
        float v = als[s * 8 + hd] + ad;
        v = v >= 0.f ? v : kSlope * v;
        const char* hp = (const char*)h2 + (size_t)s * 320 + hd * 40;
        float hv[D_OUT];
        #pragma unroll
        for (int p = 0; p < 5; ++p) {
            sh4 t = *(const sh4*)(hp + p * 8);
            #pragma unroll
            for (int j = 0; j < 4; ++j) hv[p * 4 + j] = bf2f(t[j]);
        }
        if (v <= m) {
            float w = expf(v - m);
            sum += w;
            #pragma unroll
            for (int c = 0; c < D_OUT; ++c) acc[c] += w * hv[c];
        } else {
            float r = expf(m - v);
            sum = sum * r + 1.f;
            #pragma unroll
            for (int c = 0; c < D_OUT; ++c) acc[c] = acc[c] * r + hv[c];
            m = v;
        }
    }
    // merge the two halves (lane ^ 1)
    float mo = __shfl_xor(m, 1);
    float so = __shfl_xor(sum, 1);
    float mm = fmaxf(m, mo);
    float w1 = expf(m - mm);
    float w2 = expf(mo - mm);
    sum = sum * w1 + so * w2;
    #pragma unroll
    for (int c = 0; c < D_OUT; ++c)
        acc[c] = acc[c] * w1 + __shfl_xor(acc[c], 1) * w2;
    float inv = 1.f / (sum + 1e-16f);
    // head mean across bits 1..3
    #pragma unroll
    for (int c = 0; c < D_OUT; ++c) {
        float v = acc[c] * inv;
        v += __shfl_xor(v, 2);
        v += __shfl_xor(v, 4);
        v += __shfl_xor(v, 8);
        acc[c] = v;
    }
    if (sub == 0) {
        float vals[D_OUT];
        float mx = -1e30f;
        #pragma unroll
        for (int c = 0; c < D_OUT; ++c) {
            vals[c] = 0.125f * acc[c] + b2[c];
            mx = fmaxf(mx, vals[c]);
        }
        float s = 0.f;
        #pragma unroll
        for (int c = 0; c < D_OUT; ++c) s += expf(vals[c] - mx);
        float lse = mx + logf(s);
        float* op = out + (size_t)dst * D_OUT;
        #pragma unroll
        for (int c = 0; c < D_OUT; ++c) op[c] = vals[c] - lse;
    }
}

extern "C" void kernel_launch(void* const* d_in, const int* in_sizes, int n_in,
                              void* d_out, int out_size, void* d_ws, size_t ws_size,
                              hipStream_t stream) {
    const float* x      = (const float*)d_in[0];
    const int*   ei     = (const int*)d_in[1];
    const float* gamma  = (const float*)d_in[2];
    const float* beta   = (const float*)d_in[3];
    const float* W1     = (const float*)d_in[4];
    const float* a_src1 = (const float*)d_in[5];
    const float* a_dst1 = (const float*)d_in[6];
    const float* b1     = (const float*)d_in[7];
    const float* W2     = (const float*)d_in[8];
    const float* a_src2 = (const float*)d_in[9];
    const float* a_dst2 = (const float*)d_in[10];
    const float* b2     = (const float*)d_in[11];
    float* out = (float*)d_out;
    (void)n_in; (void)out_size; (void)ws_size;

    const int E  = in_sizes[1] / 2;
    const int TE = E + N_NODES;

    char* wsb = (char*)d_ws;
    size_t off = 0;
    auto alloc = [&](size_t bytes) -> void* {
        void* p = wsb + off;
        off += (bytes + 255) & ~(size_t)255;
        return p;
    };
    float* cs    = (float*)alloc(D_IN * sizeof(float));   // adjacent to cs2 (one memset)
    float* cs2   = (float*)alloc(D_IN * sizeof(float));
    float* scale = (float*)alloc(D_IN * sizeof(float));
    float* shift = (float*)alloc(D_IN * sizeof(float));
    short* W1t   = (short*)alloc((size_t)64 * KPAD * sizeof(short));
    short* W2t   = (short*)alloc((size_t)160 * 64 * sizeof(short));
    float* c1    = (float*)alloc(64 * sizeof(float));
    short* h1b   = (short*)alloc((size_t)N_NODES * 64 * sizeof(short));
    short* h2b   = (short*)alloc((size_t)N_NODES * 160 * sizeof(short));
    float* als   = (float*)alloc((size_t)N_NODES * N_HEAD * sizeof(float));
    float* ald   = (float*)alloc((size_t)N_NODES * N_HEAD * sizeof(float));
    float* als2  = (float*)alloc((size_t)N_NODES * N_HEAD * sizeof(float));
    float* ald2  = (float*)alloc((size_t)N_NODES * N_HEAD * sizeof(float));
    int*   deg   = (int*)alloc((size_t)N_NODES * sizeof(int));
    int*   rs    = (int*)alloc((size_t)(N_NODES + 1) * sizeof(int));
    int*   cur   = (int*)alloc((size_t)N_NODES * sizeof(int));
    int*   csum  = (int*)alloc((size_t)NCH * sizeof(int));
    int*   srcs  = (int*)alloc((size_t)TE * sizeof(int));

    int egrid = (TE + 255) / 256;

    // ---- CSR build ----
    hipMemsetAsync(deg, 0, (size_t)N_NODES * sizeof(int), stream);
    k_deg<<<egrid, 256, 0, stream>>>(ei, E, TE, deg);
    k_scan_a<<<NCH, 256, 0, stream>>>(deg, csum);
    k_scan_b<<<1, 64, 0, stream>>>(csum, TE, rs);
    k_scan_c<<<NCH, 256, 0, stream>>>(deg, csum, rs, cur);
    k_fill<<<egrid, 256, 0, stream>>>(ei, E, TE, cur, srcs);

    // ---- BN stats + weight folding ----
    hipMemsetAsync(cs, 0, 8192, stream);  // cs (4096-pad) + cs2 contiguous
    k_bn_partial<<<1000, 256, 0, stream>>>(x, cs, cs2, 100);
    k_bn_finalize<<<(D_IN + 255) / 256, 256, 0, stream>>>(cs, cs2, gamma, beta, scale, shift);
    k_prep<<<297, 256, 0, stream>>>(W1, W2, scale, shift, W1t, W2t, c1);

    // ---- layer 1 GEMM + att1 logits ----
    k_gemm1<<<(N_NODES + BM - 1) / BM, 256, 0, stream>>>(x, W1t, c1, a_src1, a_dst1,
                                                          h1b, als, ald);

    // ---- fused gather1 + gemm2 + att2 logits ----
    k_fused_l2<<<(N_NODES + 127) / 128, 512, 0, stream>>>(rs, srcs, als, ald, h1b, b1,
                                                           W2t, a_src2, a_dst2,
                                                           h2b, als2, ald2);

    // ---- layer-2 gather + output ----
    k_gather2<<<(N_NODES * 16 + 255) / 256, 256, 0, stream>>>(rs, srcs, als2, ald2,
                                                               h2b, b2, out);
}